// Round 1
// baseline (34018.753 us; speedup 1.0000x reference)
//
#include <hip/hip_runtime.h>
#include <math.h>

#define T_ 128
#define B_ 64
#define E_ 300
#define H_ 2048

// ---------------- init: zero h (both pings) and c ----------------
__global__ void init_state(float* __restrict__ hbuf, float* __restrict__ cbuf) {
    int n_h = 2 * 2 * H_ * B_;   // [ping][dir][H][B]
    int n_c = 2 * H_ * B_;       // [dir][H][B]
    int stride = gridDim.x * blockDim.x;
    int i = blockIdx.x * blockDim.x + threadIdx.x;
    for (int idx = i; idx < n_h; idx += stride) hbuf[idx] = 0.f;
    for (int idx = i; idx < n_c; idx += stride) cbuf[idx] = 0.f;
}

// ---------------- gather + transpose: x_t[t][e][b] = embed[tokens[t,b]][e] ----------------
__global__ void gather_x(const int* __restrict__ tokens,
                         const float* __restrict__ embed,
                         float* __restrict__ x_t) {
    int idx = blockIdx.x * blockDim.x + threadIdx.x;
    int total = T_ * E_ * B_;
    if (idx >= total) return;
    int b = idx % B_;
    int r = idx / B_;
    int e = r % E_;
    int t = r / E_;
    int tok = tokens[t * B_ + b];
    x_t[idx] = embed[tok * E_ + e];
}

__device__ __forceinline__ float sigm(float x) {
    return 1.f / (1.f + expf(-x));
}

// ---------------- one LSTM timestep, both directions ----------------
// grid: 512 blocks = 2 dirs x 256 kblocks; block: 256 threads
// thread: (bpair = tid&31 -> b0=2*bpair, kloc = tid>>5) ; k = kblk*8 + kloc
// computes all 4 gates for (b0,b0+1, k), then updates c,h and captures outputs.
__global__ __launch_bounds__(256) void lstm_step(
    const float* __restrict__ x_t,    // [T][E][B]
    const float* __restrict__ W_ih,   // [4H][E]
    const float* __restrict__ W_hh,   // [4H][H]
    const float* __restrict__ b_ih,   // [4H]
    const float* __restrict__ b_hh,   // [4H]
    const int*   __restrict__ lens,   // [B]
    const float* __restrict__ h_in,   // [dir][H][B]
    float*       __restrict__ h_out,  // [dir][H][B]
    float*       __restrict__ cbuf,   // [dir][H][B]
    float*       __restrict__ out,    // [B][2H]
    int t)
{
    const int dir   = blockIdx.x >> 8;
    const int kblk  = blockIdx.x & 255;
    const int bpair = threadIdx.x & 31;
    const int kloc  = threadIdx.x >> 5;
    const int k     = kblk * 8 + kloc;
    const int b0    = bpair * 2;

    const int xt = dir ? (T_ - 1 - t) : t;
    const float* __restrict__ xrow = x_t + (size_t)xt * E_ * B_;
    const float* __restrict__ hrow = h_in + (size_t)dir * H_ * B_;

    float a0x = 0.f, a0y = 0.f, a1x = 0.f, a1y = 0.f;
    float a2x = 0.f, a2y = 0.f, a3x = 0.f, a3y = 0.f;

    // ---- x part: K = E = 300 ----
    {
        const float* __restrict__ w0 = W_ih + (size_t)(0 * H_ + k) * E_;
        const float* __restrict__ w1 = W_ih + (size_t)(1 * H_ + k) * E_;
        const float* __restrict__ w2 = W_ih + (size_t)(2 * H_ + k) * E_;
        const float* __restrict__ w3 = W_ih + (size_t)(3 * H_ + k) * E_;
        #pragma unroll 4
        for (int kk = 0; kk < E_; ++kk) {
            float2 xv = *(const float2*)(xrow + kk * B_ + b0);
            float c0 = w0[kk], c1 = w1[kk], c2 = w2[kk], c3 = w3[kk];
            a0x += xv.x * c0; a0y += xv.y * c0;
            a1x += xv.x * c1; a1y += xv.y * c1;
            a2x += xv.x * c2; a2y += xv.y * c2;
            a3x += xv.x * c3; a3y += xv.y * c3;
        }
    }
    // ---- h part: K = H = 2048 ----
    {
        const float* __restrict__ w0 = W_hh + (size_t)(0 * H_ + k) * H_;
        const float* __restrict__ w1 = W_hh + (size_t)(1 * H_ + k) * H_;
        const float* __restrict__ w2 = W_hh + (size_t)(2 * H_ + k) * H_;
        const float* __restrict__ w3 = W_hh + (size_t)(3 * H_ + k) * H_;
        #pragma unroll 4
        for (int kk = 0; kk < H_; ++kk) {
            float2 hv = *(const float2*)(hrow + kk * B_ + b0);
            float c0 = w0[kk], c1 = w1[kk], c2 = w2[kk], c3 = w3[kk];
            a0x += hv.x * c0; a0y += hv.y * c0;
            a1x += hv.x * c1; a1y += hv.y * c1;
            a2x += hv.x * c2; a2y += hv.y * c2;
            a3x += hv.x * c3; a3y += hv.y * c3;
        }
    }

    const int j0 = 0 * H_ + k, j1 = 1 * H_ + k, j2 = 2 * H_ + k, j3 = 3 * H_ + k;
    const float bi = b_ih[j0] + b_hh[j0];
    const float bf = b_ih[j1] + b_hh[j1];
    const float bg = b_ih[j2] + b_hh[j2];
    const float bo = b_ih[j3] + b_hh[j3];

    float* __restrict__ cdir = cbuf + (size_t)dir * H_ * B_;
    float* __restrict__ hdir = h_out + (size_t)dir * H_ * B_;

    #pragma unroll
    for (int s = 0; s < 2; ++s) {
        const int b = b0 + s;
        const float ai = (s == 0) ? a0x : a0y;
        const float af = (s == 0) ? a1x : a1y;
        const float ag = (s == 0) ? a2x : a2y;
        const float ao = (s == 0) ? a3x : a3y;

        const float iv = sigm(ai + bi);
        const float fv = sigm(af + bf);
        const float gv = tanhf(ag + bg);
        const float ov = sigm(ao + bo);

        const int sidx = k * B_ + b;
        const float c_old = cdir[sidx];
        const float c_new = fv * c_old + iv * gv;
        cdir[sidx] = c_new;
        const float h_new = ov * tanhf(c_new);
        hdir[sidx] = h_new;

        if (dir == 0) {
            if (t == lens[b] - 1) out[(size_t)b * (2 * H_) + k] = h_new;
        } else {
            if (t == T_ - 1) out[(size_t)b * (2 * H_) + H_ + k] = h_new;
        }
    }
}

extern "C" void kernel_launch(void* const* d_in, const int* in_sizes, int n_in,
                              void* d_out, int out_size, void* d_ws, size_t ws_size,
                              hipStream_t stream) {
    const int*   tokens = (const int*)d_in[0];
    const int*   lens   = (const int*)d_in[1];
    const float* embed  = (const float*)d_in[2];
    const float* W_ih   = (const float*)d_in[3];
    const float* W_hh   = (const float*)d_in[4];
    const float* b_ih   = (const float*)d_in[5];
    const float* b_hh   = (const float*)d_in[6];
    float* out = (float*)d_out;

    float* ws   = (float*)d_ws;
    float* x_t  = ws;                                   // T*E*B   = 2,457,600 f
    float* hbuf = x_t + (size_t)T_ * E_ * B_;           // 2*2*H*B =   524,288 f
    float* cbuf = hbuf + (size_t)2 * 2 * H_ * B_;       // 2*H*B   =   262,144 f
    // total ~13 MB of workspace

    init_state<<<256, 256, 0, stream>>>(hbuf, cbuf);

    {
        int total = T_ * E_ * B_;
        gather_x<<<(total + 255) / 256, 256, 0, stream>>>(tokens, embed, x_t);
    }

    for (int t = 0; t < T_; ++t) {
        const float* h_in  = hbuf + (size_t)(t & 1) * 2 * H_ * B_;
        float*       h_out = hbuf + (size_t)((t + 1) & 1) * 2 * H_ * B_;
        lstm_step<<<512, 256, 0, stream>>>(x_t, W_ih, W_hh, b_ih, b_hh, lens,
                                           h_in, h_out, cbuf, out, t);
    }
}

// Round 2
// 11007.236 us; speedup vs baseline: 3.0906x; 3.0906x over previous
//
#include <hip/hip_runtime.h>
#include <math.h>

#define T_ 128
#define B_ 64
#define E_ 300
#define H_ 2048

// ---- MFMA-path geometry ----
#define K1    2368   // padded K per segment: [0,304) x | [304,2352) h | pad
#define EPAD  304
#define HOFF  304
#define HEND  2352
#define SEGSTEPS 74          // 2368/32
#define REALSTEPS 222        // 3*74
#define TOTSTEPS 224         // padded to /4
#define SPLITSTEPS 56        // per K-split

typedef __attribute__((ext_vector_type(8))) short short8;
typedef __attribute__((ext_vector_type(4))) float float4v;

__device__ __forceinline__ unsigned f2bf(float f) {
    unsigned u = __float_as_uint(f);
    return (u + 0x7FFFu + ((u >> 16) & 1u)) >> 16;
}
__device__ __forceinline__ float bf2f(unsigned b) { return __uint_as_float(b << 16); }

__device__ __forceinline__ void gl_lds16(const void* g, void* l) {
    __builtin_amdgcn_global_load_lds(
        (const __attribute__((address_space(1))) unsigned int*)g,
        (__attribute__((address_space(3))) unsigned int*)l, 16, 0, 0);
}

__device__ __forceinline__ float sigm(float x) { return 1.f / (1.f + expf(-x)); }

// ================= prologue kernels =================

// zero hbuf (both pings, hi/lo, dirs), cbuf, zeros scratch
__global__ void init_ws2(short* __restrict__ hb, float* __restrict__ cb,
                         short* __restrict__ zer) {
    const int nH = 2 * 2 * 2 * 64 * 2048;   // shorts
    const int nC = 2 * 2048 * 64;           // floats
    int stride = gridDim.x * blockDim.x;
    int i = blockIdx.x * blockDim.x + threadIdx.x;
    for (int idx = i; idx < nH; idx += stride) hb[idx] = 0;
    for (int idx = i; idx < nC; idx += stride) cb[idx] = 0.f;
    for (int idx = i; idx < 128; idx += stride) zer[idx] = 0;
}

// Whi/Wlo[j][K1]: cols [0,300)=W_ih, [304,2352)=W_hh, else 0
__global__ void conv_w(const float* __restrict__ Wih, const float* __restrict__ Whh,
                       short* __restrict__ whi, short* __restrict__ wlo) {
    int idx = blockIdx.x * blockDim.x + threadIdx.x;
    const int total = 8192 * K1;
    if (idx >= total) return;
    int j = idx / K1;
    int col = idx - j * K1;
    float w = 0.f;
    if (col < E_) w = Wih[(size_t)j * E_ + col];
    else if (col >= HOFF && col < HEND) w = Whh[(size_t)j * H_ + (col - HOFF)];
    unsigned hb = f2bf(w);
    whi[idx] = (short)hb;
    wlo[idx] = (short)f2bf(w - bf2f(hb));
}

// xhi/xlo[t][b][EPAD] from embed[tokens]
__global__ void conv_x(const int* __restrict__ tokens, const float* __restrict__ embed,
                       short* __restrict__ xhi, short* __restrict__ xlo) {
    int idx = blockIdx.x * blockDim.x + threadIdx.x;
    const int total = T_ * B_ * EPAD;
    if (idx >= total) return;
    int t = idx / (B_ * EPAD);
    int r = idx - t * (B_ * EPAD);
    int bb = r / EPAD;
    int e = r - bb * EPAD;
    float v = 0.f;
    if (e < E_) {
        int tok = tokens[t * B_ + bb];
        v = embed[(size_t)tok * E_ + e];
    }
    unsigned hb = f2bf(v);
    xhi[idx] = (short)hb;
    xlo[idx] = (short)f2bf(v - bf2f(hb));
}

// ================= per-step GEMM partial =================
// grid 256 = dir(1)<<7 | kt(5)<<2 | split(2); 512 threads = 8 waves
// C_partial[j'(256 = 4 gates x 64 k), b(64)] += W[j, K-slice] * v[K-slice, b]
__global__ __launch_bounds__(512) void gemm_partial(
    const short* __restrict__ Whi, const short* __restrict__ Wlo,
    const short* __restrict__ xhi, const short* __restrict__ xlo,
    const short* __restrict__ hbuf,   // [ping][hl][dir][b][2048] bf16
    const short* __restrict__ zeros,
    float* __restrict__ pbuf, int t)
{
    __shared__ short As[2][8192];   // [c:4][row:256][8] bf16
    __shared__ short Bs[2][2048];   // [c:4][b:64][8]   bf16

    const int bx  = blockIdx.x;
    const int s   = bx & 3;
    const int kt  = (bx >> 2) & 31;
    const int dir = bx >> 7;
    const int tid = threadIdx.x;
    const int w   = tid >> 6;
    const int l   = tid & 63;
    const int ping = t & 1;
    const int xt   = dir ? (T_ - 1 - t) : t;

    // A-staging lane geometry (2 issues/wave)
    int jA[2], cA[2];
#pragma unroll
    for (int q = 0; q < 2; ++q) {
        int idx = (w * 2 + q) * 64 + l;
        cA[q] = idx >> 8;
        int row = idx & 255;
        jA[q] = (row >> 6) * 2048 + kt * 64 + (row & 63);
    }
    // B-staging lane geometry (waves 0-3, 1 issue)
    int cB = 0, bB = 0;
    if (w < 4) { int idx = w * 64 + l; cB = idx >> 6; bB = idx & 63; }

    const int lhi = l >> 4, llo = l & 15;
    const int rowbase = (w >> 1) * 64 + (w & 1) * 32;

    float4v acc[2][4];
#pragma unroll
    for (int a = 0; a < 2; ++a)
#pragma unroll
        for (int b = 0; b < 4; ++b) acc[a][b] = (float4v){0.f, 0.f, 0.f, 0.f};

    auto stage = [&](int g, int buf) {
        const bool dummy = (g >= REALSTEPS);
        const int seg = dummy ? 2 : g / SEGSTEPS;
        const int ss  = dummy ? 0 : g - seg * SEGSTEPS;
        const int kbase = ss * 32;
        const short* Wsel = (seg < 2) ? Whi : Wlo;
        const int hl = (seg == 1) ? 1 : 0;
        const short* xsel = (seg == 1) ? xlo : xhi;
        const short* hsel = hbuf + (((size_t)ping * 2 + hl) * 2 + dir) * (64 * 2048);
#pragma unroll
        for (int q = 0; q < 2; ++q) {
            const short* src = Wsel + (size_t)jA[q] * K1 + kbase + 8 * cA[q];
            gl_lds16(src, &As[buf][(w * 2 + q) * 64 * 8]);
        }
        if (w < 4) {
            int row8 = kbase + 8 * cB;
            const short* src;
            if (dummy || row8 >= HEND) src = zeros;
            else if (row8 < EPAD)      src = xsel + ((size_t)xt * 64 + bB) * EPAD + row8;
            else                       src = hsel + (size_t)bB * 2048 + (row8 - HOFF);
            gl_lds16(src, &Bs[buf][w * 64 * 8]);
        }
    };

    const int g0 = s * SPLITSTEPS;
    stage(g0, 0);

    for (int it = 0; it < SPLITSTEPS; ++it) {
        const int buf = it & 1;
        if (it + 1 < SPLITSTEPS) stage(g0 + it + 1, buf ^ 1);
        __syncthreads();   // drains vmcnt -> buf ready
        // compute on buf
        short8 a0 = *(const short8*)&As[buf][(lhi * 256 + rowbase + llo) * 8];
        short8 a1 = *(const short8*)&As[buf][(lhi * 256 + rowbase + 16 + llo) * 8];
        short8 b0 = *(const short8*)&Bs[buf][(lhi * 64 + llo) * 8];
        short8 b1 = *(const short8*)&Bs[buf][(lhi * 64 + 16 + llo) * 8];
        short8 b2 = *(const short8*)&Bs[buf][(lhi * 64 + 32 + llo) * 8];
        short8 b3 = *(const short8*)&Bs[buf][(lhi * 64 + 48 + llo) * 8];
        acc[0][0] = __builtin_amdgcn_mfma_f32_16x16x32_bf16(a0, b0, acc[0][0], 0, 0, 0);
        acc[0][1] = __builtin_amdgcn_mfma_f32_16x16x32_bf16(a0, b1, acc[0][1], 0, 0, 0);
        acc[0][2] = __builtin_amdgcn_mfma_f32_16x16x32_bf16(a0, b2, acc[0][2], 0, 0, 0);
        acc[0][3] = __builtin_amdgcn_mfma_f32_16x16x32_bf16(a0, b3, acc[0][3], 0, 0, 0);
        acc[1][0] = __builtin_amdgcn_mfma_f32_16x16x32_bf16(a1, b0, acc[1][0], 0, 0, 0);
        acc[1][1] = __builtin_amdgcn_mfma_f32_16x16x32_bf16(a1, b1, acc[1][1], 0, 0, 0);
        acc[1][2] = __builtin_amdgcn_mfma_f32_16x16x32_bf16(a1, b2, acc[1][2], 0, 0, 0);
        acc[1][3] = __builtin_amdgcn_mfma_f32_16x16x32_bf16(a1, b3, acc[1][3], 0, 0, 0);
        __syncthreads();   // protect buf from next stage
    }

    float* pb = pbuf + (((size_t)(dir * 32 + kt) * 4 + s) * 256) * 64;
#pragma unroll
    for (int qm = 0; qm < 2; ++qm)
#pragma unroll
        for (int nb = 0; nb < 4; ++nb)
#pragma unroll
            for (int r = 0; r < 4; ++r) {
                int row = rowbase + qm * 16 + lhi * 4 + r;
                int col = nb * 16 + llo;
                pb[row * 64 + col] = acc[qm][nb][r];
            }
}

// ================= per-step update =================
// grid 64 = dir(1)<<5 | kt(5); 256 threads
__global__ __launch_bounds__(256) void lstm_update(
    const float* __restrict__ pbuf,
    const float* __restrict__ b_ih, const float* __restrict__ b_hh,
    const int* __restrict__ lens,
    float* __restrict__ cbuf,        // [dir][2048][64] f32
    short* __restrict__ hbuf,        // [ping][hl][dir][b][2048] bf16
    float* __restrict__ out, int t)
{
    const int bx = blockIdx.x;
    const int kt = bx & 31, dir = bx >> 5;
    const float* pb = pbuf + (size_t)(dir * 32 + kt) * 4 * 256 * 64;
    const int ping = (t + 1) & 1;   // write ping

    for (int idx = threadIdx.x; idx < 4096; idx += 256) {
        const int q = idx >> 6, bb = idx & 63;
        const int k = kt * 64 + q;
        float gv[4];
#pragma unroll
        for (int gg = 0; gg < 4; ++gg) {
            const int r = gg * 64 + q;
            float v = 0.f;
#pragma unroll
            for (int s2 = 0; s2 < 4; ++s2) v += pb[(s2 * 256 + r) * 64 + bb];
            const int j = gg * 2048 + k;
            gv[gg] = v + b_ih[j] + b_hh[j];
        }
        const float iv = sigm(gv[0]);
        const float fv = sigm(gv[1]);
        const float g2 = tanhf(gv[2]);
        const float ov = sigm(gv[3]);
        const size_t cidx = ((size_t)dir * 2048 + k) * 64 + bb;
        const float c = fv * cbuf[cidx] + iv * g2;
        cbuf[cidx] = c;
        const float h = ov * tanhf(c);

        const unsigned hb = f2bf(h);
        const float hhi = bf2f(hb);
        const unsigned lb = f2bf(h - hhi);
        const size_t basehi = (((size_t)ping * 2 + 0) * 2 + dir) * (64 * 2048);
        const size_t baselo = (((size_t)ping * 2 + 1) * 2 + dir) * (64 * 2048);
        hbuf[basehi + (size_t)bb * 2048 + k] = (short)hb;
        hbuf[baselo + (size_t)bb * 2048 + k] = (short)lb;

        if (dir == 0) {
            if (t == lens[bb] - 1) out[(size_t)bb * (2 * H_) + k] = h;
        } else {
            if (t == T_ - 1) out[(size_t)bb * (2 * H_) + H_ + k] = h;
        }
    }
}

// ================= fallback (round-1) path =================
__global__ void init_state(float* __restrict__ hbuf, float* __restrict__ cbuf) {
    int n_h = 2 * 2 * H_ * B_;
    int n_c = 2 * H_ * B_;
    int stride = gridDim.x * blockDim.x;
    int i = blockIdx.x * blockDim.x + threadIdx.x;
    for (int idx = i; idx < n_h; idx += stride) hbuf[idx] = 0.f;
    for (int idx = i; idx < n_c; idx += stride) cbuf[idx] = 0.f;
}

__global__ void gather_x(const int* __restrict__ tokens, const float* __restrict__ embed,
                         float* __restrict__ x_t) {
    int idx = blockIdx.x * blockDim.x + threadIdx.x;
    int total = T_ * E_ * B_;
    if (idx >= total) return;
    int b = idx % B_;
    int r = idx / B_;
    int e = r % E_;
    int t = r / E_;
    int tok = tokens[t * B_ + b];
    x_t[idx] = embed[tok * E_ + e];
}

__global__ __launch_bounds__(256) void lstm_step(
    const float* __restrict__ x_t, const float* __restrict__ W_ih,
    const float* __restrict__ W_hh, const float* __restrict__ b_ih,
    const float* __restrict__ b_hh, const int* __restrict__ lens,
    const float* __restrict__ h_in, float* __restrict__ h_out,
    float* __restrict__ cbuf, float* __restrict__ out, int t)
{
    const int dir = blockIdx.x >> 8;
    const int kblk = blockIdx.x & 255;
    const int bpair = threadIdx.x & 31;
    const int kloc = threadIdx.x >> 5;
    const int k = kblk * 8 + kloc;
    const int b0 = bpair * 2;
    const int xt = dir ? (T_ - 1 - t) : t;
    const float* xrow = x_t + (size_t)xt * E_ * B_;
    const float* hrow = h_in + (size_t)dir * H_ * B_;
    float a0x = 0.f, a0y = 0.f, a1x = 0.f, a1y = 0.f;
    float a2x = 0.f, a2y = 0.f, a3x = 0.f, a3y = 0.f;
    {
        const float* w0 = W_ih + (size_t)(0 * H_ + k) * E_;
        const float* w1 = W_ih + (size_t)(1 * H_ + k) * E_;
        const float* w2 = W_ih + (size_t)(2 * H_ + k) * E_;
        const float* w3 = W_ih + (size_t)(3 * H_ + k) * E_;
#pragma unroll 4
        for (int kk = 0; kk < E_; ++kk) {
            float2 xv = *(const float2*)(xrow + kk * B_ + b0);
            float c0 = w0[kk], c1 = w1[kk], c2 = w2[kk], c3 = w3[kk];
            a0x += xv.x * c0; a0y += xv.y * c0;
            a1x += xv.x * c1; a1y += xv.y * c1;
            a2x += xv.x * c2; a2y += xv.y * c2;
            a3x += xv.x * c3; a3y += xv.y * c3;
        }
    }
    {
        const float* w0 = W_hh + (size_t)(0 * H_ + k) * H_;
        const float* w1 = W_hh + (size_t)(1 * H_ + k) * H_;
        const float* w2 = W_hh + (size_t)(2 * H_ + k) * H_;
        const float* w3 = W_hh + (size_t)(3 * H_ + k) * H_;
#pragma unroll 4
        for (int kk = 0; kk < H_; ++kk) {
            float2 hv = *(const float2*)(hrow + kk * B_ + b0);
            float c0 = w0[kk], c1 = w1[kk], c2 = w2[kk], c3 = w3[kk];
            a0x += hv.x * c0; a0y += hv.y * c0;
            a1x += hv.x * c1; a1y += hv.y * c1;
            a2x += hv.x * c2; a2y += hv.y * c2;
            a3x += hv.x * c3; a3y += hv.y * c3;
        }
    }
    const int j0 = 0 * H_ + k, j1 = 1 * H_ + k, j2 = 2 * H_ + k, j3 = 3 * H_ + k;
    const float bi = b_ih[j0] + b_hh[j0];
    const float bf = b_ih[j1] + b_hh[j1];
    const float bg = b_ih[j2] + b_hh[j2];
    const float bo = b_ih[j3] + b_hh[j3];
    float* cdir = cbuf + (size_t)dir * H_ * B_;
    float* hdir = h_out + (size_t)dir * H_ * B_;
#pragma unroll
    for (int s = 0; s < 2; ++s) {
        const int b = b0 + s;
        const float ai = (s == 0) ? a0x : a0y;
        const float af = (s == 0) ? a1x : a1y;
        const float ag = (s == 0) ? a2x : a2y;
        const float ao = (s == 0) ? a3x : a3y;
        const float iv = sigm(ai + bi);
        const float fv = sigm(af + bf);
        const float gv = tanhf(ag + bg);
        const float ov = sigm(ao + bo);
        const int sidx = k * B_ + b;
        const float c_old = cdir[sidx];
        const float c_new = fv * c_old + iv * gv;
        cdir[sidx] = c_new;
        const float h_new = ov * tanhf(c_new);
        hdir[sidx] = h_new;
        if (dir == 0) {
            if (t == lens[b] - 1) out[(size_t)b * (2 * H_) + k] = h_new;
        } else {
            if (t == T_ - 1) out[(size_t)b * (2 * H_) + H_ + k] = h_new;
        }
    }
}

// ================= launch =================
extern "C" void kernel_launch(void* const* d_in, const int* in_sizes, int n_in,
                              void* d_out, int out_size, void* d_ws, size_t ws_size,
                              hipStream_t stream) {
    const int*   tokens = (const int*)d_in[0];
    const int*   lens   = (const int*)d_in[1];
    const float* embed  = (const float*)d_in[2];
    const float* W_ih   = (const float*)d_in[3];
    const float* W_hh   = (const float*)d_in[4];
    const float* b_ih   = (const float*)d_in[5];
    const float* b_hh   = (const float*)d_in[6];
    float* out = (float*)d_out;

    // ws layout (bytes, all 16B-aligned)
    const size_t SZ_W  = (size_t)8192 * K1;          // shorts per W buffer
    const size_t SZ_X  = (size_t)T_ * B_ * EPAD;     // shorts per x buffer
    const size_t SZ_HB = (size_t)2 * 2 * 2 * 64 * 2048; // shorts
    const size_t SZ_CB = (size_t)2 * 2048 * 64;      // floats
    const size_t SZ_PB = (size_t)64 * 4 * 256 * 64;  // floats

    short* Whi  = (short*)d_ws;
    short* Wlo  = Whi + SZ_W;
    short* xhiB = Wlo + SZ_W;
    short* xloB = xhiB + SZ_X;
    short* hb2  = xloB + SZ_X;
    short* zer  = hb2 + SZ_HB;
    float* cb2  = (float*)(zer + 128);
    float* pbuf = cb2 + SZ_CB;
    const size_t required = (size_t)((char*)(pbuf + SZ_PB) - (char*)d_ws);

    if (ws_size >= required) {
        // ---- MFMA split-precision path ----
        init_ws2<<<1024, 256, 0, stream>>>(hb2, cb2, zer);
        {
            int total = 8192 * K1;
            conv_w<<<(total + 255) / 256, 256, 0, stream>>>(W_ih, W_hh, Whi, Wlo);
        }
        {
            int total = T_ * B_ * EPAD;
            conv_x<<<(total + 255) / 256, 256, 0, stream>>>(tokens, embed, xhiB, xloB);
        }
        for (int t = 0; t < T_; ++t) {
            gemm_partial<<<256, 512, 0, stream>>>(Whi, Wlo, xhiB, xloB, hb2, zer, pbuf, t);
            lstm_update<<<64, 256, 0, stream>>>(pbuf, b_ih, b_hh, lens, cb2, hb2, out, t);
        }
    } else {
        // ---- fallback: round-1 fp32 path (needs ~13 MB) ----
        float* ws   = (float*)d_ws;
        float* x_t  = ws;
        float* hbuf = x_t + (size_t)T_ * E_ * B_;
        float* cbuf = hbuf + (size_t)2 * 2 * H_ * B_;
        init_state<<<256, 256, 0, stream>>>(hbuf, cbuf);
        {
            int total = T_ * E_ * B_;
            gather_x<<<(total + 255) / 256, 256, 0, stream>>>(tokens, embed, x_t);
        }
        for (int t = 0; t < T_; ++t) {
            const float* h_in  = hbuf + (size_t)(t & 1) * 2 * H_ * B_;
            float*       h_out = hbuf + (size_t)((t + 1) & 1) * 2 * H_ * B_;
            lstm_step<<<512, 256, 0, stream>>>(x_t, W_ih, W_hh, b_ih, b_hh, lens,
                                               h_in, h_out, cbuf, out, t);
        }
    }
}

// Round 3
// 5071.848 us; speedup vs baseline: 6.7074x; 2.1703x over previous
//
#include <hip/hip_runtime.h>
#include <math.h>

#define T_ 128
#define B_ 64
#define E_ 300
#define H_ 2048

// ======== new-path geometry ========
// K layout: [0,300) x | [300,320) zero-pad | [320,2368) h   -> K1 = 2368 = 74 ksteps of 32
#define K1   2368
#define XKS  10      // x ksteps (320/32)
#define NKS  74      // total ksteps
#define APELEMS 19398656ull   // 8192 * 2368, per weight matrix (frag-major packed)
#define BXELEMS 5242880ull    // 128 t * 10 ks * 2 hl * 4 nf * 64 l * 8 j
#define BHPING  524288ull     // 64 ks * 16 nf * 64 l * 8 j   (shorts per ping)

typedef __attribute__((ext_vector_type(8))) short short8;
typedef __attribute__((ext_vector_type(4))) float float4v;

__device__ __forceinline__ unsigned f2bf(float f) {
    unsigned u = __float_as_uint(f);
    return (u + 0x7FFFu + ((u >> 16) & 1u)) >> 16;
}
__device__ __forceinline__ float bf2f(unsigned b) { return __uint_as_float(b << 16); }

__device__ __forceinline__ void gl_lds16(const void* g, void* l) {
    __builtin_amdgcn_global_load_lds(
        (const __attribute__((address_space(1))) unsigned int*)g,
        (__attribute__((address_space(3))) unsigned int*)l, 16, 0, 0);
}

__device__ __forceinline__ float sigm(float x) { return 1.f / (1.f + expf(-x)); }

// ================= new-path prologue =================

__global__ void init2(short* __restrict__ Bh, float* __restrict__ cb) {
    const int nB = 2 * (int)BHPING;     // shorts
    const int nC = 2 * 2048 * 64;       // floats
    int stride = gridDim.x * blockDim.x;
    int i = blockIdx.x * blockDim.x + threadIdx.x;
    for (int idx = i; idx < nB; idx += stride) Bh[idx] = 0;
    for (int idx = i; idx < nC; idx += stride) cb[idx] = 0.f;
}

// frag-major packed weights: [rb(64)][ks(74)][mf(8)][l(64)][j(8)]
// element = W[row = rb*128+mf*16+(l&15)][kr = ks*32+(l>>4)*8+j]
__global__ void pack_w(const float* __restrict__ Wih, const float* __restrict__ Whh,
                       short* __restrict__ Ahi, short* __restrict__ Alo) {
    long long idx = (long long)blockIdx.x * blockDim.x + threadIdx.x;
    if (idx >= (long long)APELEMS) return;
    int j  = (int)(idx & 7);
    int l  = (int)((idx >> 3) & 63);
    int mf = (int)((idx >> 9) & 7);
    int rest = (int)(idx >> 12);
    int ks = rest % 74;
    int rb = rest / 74;
    int row = rb * 128 + mf * 16 + (l & 15);
    int kr  = ks * 32 + (l >> 4) * 8 + j;
    float wv = 0.f;
    if (kr < 300)       wv = Wih[(size_t)row * 300 + kr];
    else if (kr >= 320) wv = Whh[(size_t)row * 2048 + (kr - 320)];
    unsigned hb = f2bf(wv);
    Ahi[idx] = (short)hb;
    Alo[idx] = (short)f2bf(wv - bf2f(hb));
}

// packed x: [t(128)][ks(10)][hl(2)][nf4(4)][l(64)][j(8)]
// col b = nf4*16+(l&15); kr = ks*32+(l>>4)*8+j
__global__ void pack_x(const int* __restrict__ tokens, const float* __restrict__ embed,
                       short* __restrict__ Bx) {
    long long idx = (long long)blockIdx.x * blockDim.x + threadIdx.x;
    if (idx >= (long long)BXELEMS) return;
    int j   = (int)(idx & 7);
    int l   = (int)((idx >> 3) & 63);
    int nf4 = (int)((idx >> 9) & 3);
    int hl  = (int)((idx >> 11) & 1);
    int rest = (int)(idx >> 12);
    int ks = rest % 10;
    int tt = rest / 10;
    int b  = nf4 * 16 + (l & 15);
    int kr = ks * 32 + (l >> 4) * 8 + j;
    float v = 0.f;
    if (kr < 300) {
        int tok = tokens[tt * 64 + b];
        v = embed[(size_t)tok * 300 + kr];
    }
    unsigned hb = f2bf(v);
    Bx[idx] = hl ? (short)f2bf(v - bf2f(hb)) : (short)hb;
}

// ================= new-path per-step GEMM =================
// TYPE 0 (Whi): 256 blocks = rb(64)*s(4); M=128, N=256 (cg: d0hi,d0lo,d1hi,d1lo)
//               wavegrid 2(M)x4(N); epilogue sums hi+lo col pairs -> phi[s][8192][128]
// TYPE 1 (Wlo): 256 blocks; M=128, N=128 (cg: d0hi,d1hi); wavegrid 4x2 -> plo[s][8192][128]
template<int TYPE>
__device__ __forceinline__ void gemm_body(
    int bb, short* lds,
    const short* __restrict__ Ahi, const short* __restrict__ Alo,
    const short* __restrict__ Bx, const short* __restrict__ Bh,
    float* __restrict__ phi, float* __restrict__ plo, int t)
{
    const int rb = bb >> 2, s = bb & 3;
    const int tid = (int)threadIdx.x;
    const int w = tid >> 6, l = tid & 63;
    const int ping = t & 1;
    constexpr int MF = TYPE ? 2 : 4;
    const short* Ap = TYPE ? Alo : Ahi;

    short* As = lds;          // 2 x 4096 shorts
    short* Bs = lds + 8192;   // 2 x 8192 shorts

    const int ks0 = (74 * s) >> 2, ks1 = (74 * (s + 1)) >> 2;

    float4v acc[MF][4];
#pragma unroll
    for (int i = 0; i < MF; ++i)
#pragma unroll
        for (int n = 0; n < 4; ++n) acc[i][n] = (float4v){0.f, 0.f, 0.f, 0.f};

    auto stage = [&](int ks, int buf) {
        // A: 512 chunks of 16B, linear
        {
            const short* src = Ap + ((size_t)(rb * 74 + ks) * 512 + tid) * 8;
            gl_lds16(src, As + buf * 4096 + tid * 8);
        }
        // B
        const int NB = TYPE ? 1 : 2;
#pragma unroll
        for (int q = 0; q < NB; ++q) {
            int c = q * 512 + tid;
            int nt = c >> 6, ll = c & 63;
            int dsel, hl, nf;
            if (TYPE) { dsel = nt >> 2; hl = 0; nf = dsel * 8 + (nt & 3); }
            else      { nf = nt; dsel = nf >> 3; hl = (nf >> 2) & 1; }
            const short* src;
            if (ks < XKS) {
                int xt = dsel ? (127 - t) : t;
                src = Bx + (((size_t)(xt * 10 + ks) * 2 + hl) * 4 + (nf & 3)) * 512 + ll * 8;
            } else {
                src = Bh + (size_t)ping * BHPING + ((size_t)(ks - XKS) * 16 + nf) * 512 + ll * 8;
            }
            gl_lds16(src, Bs + buf * 8192 + c * 8);
        }
    };

    const int wm = TYPE ? (w >> 1) : (w >> 2);
    const int wn = TYPE ? (w & 1) : (w & 3);

    const int nks = ks1 - ks0;
    stage(ks0, 0);
    for (int it = 0; it < nks; ++it) {
        const int buf = it & 1;
        if (it + 1 < nks) stage(ks0 + it + 1, buf ^ 1);
        __syncthreads();
        short8 a[MF], b[4];
#pragma unroll
        for (int i = 0; i < MF; ++i)
            a[i] = *(const short8*)(As + buf * 4096 + ((wm * MF + i) * 64 + l) * 8);
#pragma unroll
        for (int n = 0; n < 4; ++n)
            b[n] = *(const short8*)(Bs + buf * 8192 + ((wn * 4 + n) * 64 + l) * 8);
#pragma unroll
        for (int i = 0; i < MF; ++i)
#pragma unroll
            for (int n = 0; n < 4; ++n)
                acc[i][n] = __builtin_amdgcn_mfma_f32_16x16x32_bf16(a[i], b[n], acc[i][n], 0, 0, 0);
        __syncthreads();
    }

    if (TYPE == 0) {
        // reduce col pairs (wn 0<-1 for d0, 2<-3 for d1) via LDS, then write phi
        float* red = (float*)lds;   // 8192 floats used per round (32KB)
#pragma unroll
        for (int rnd = 0; rnd < 2; ++rnd) {
            __syncthreads();
            if (wn == rnd * 2 + 1) {
#pragma unroll
                for (int i = 0; i < 4; ++i)
#pragma unroll
                    for (int n = 0; n < 4; ++n)
                        *(float4v*)(red + ((wm * 16 + i * 4 + n) * 64 + l) * 4) = acc[i][n];
            }
            __syncthreads();
            if (wn == rnd * 2) {
#pragma unroll
                for (int i = 0; i < 4; ++i)
#pragma unroll
                    for (int n = 0; n < 4; ++n) {
                        float4v v = *(const float4v*)(red + ((wm * 16 + i * 4 + n) * 64 + l) * 4);
                        acc[i][n] += v;
                    }
            }
        }
        if (!(wn & 1)) {
            const int d = wn >> 1;
#pragma unroll
            for (int i = 0; i < 4; ++i)
#pragma unroll
                for (int n = 0; n < 4; ++n)
#pragma unroll
                    for (int r = 0; r < 4; ++r) {
                        int row = rb * 128 + wm * 64 + i * 16 + (l >> 4) * 4 + r;
                        int col = d * 64 + n * 16 + (l & 15);
                        phi[((size_t)s * 8192 + row) * 128 + col] = acc[i][n][r];
                    }
        }
    } else {
#pragma unroll
        for (int i = 0; i < 2; ++i)
#pragma unroll
            for (int n = 0; n < 4; ++n)
#pragma unroll
                for (int r = 0; r < 4; ++r) {
                    int nt = wn * 4 + n;
                    int row = rb * 128 + (wm * 2 + i) * 16 + (l >> 4) * 4 + r;
                    int col = (nt >> 2) * 64 + (nt & 3) * 16 + (l & 15);
                    plo[((size_t)s * 8192 + row) * 128 + col] = acc[i][n][r];
                }
    }
}

__global__ __launch_bounds__(512, 2) void gemm_step(
    const short* __restrict__ Ahi, const short* __restrict__ Alo,
    const short* __restrict__ Bx, const short* __restrict__ Bh,
    float* __restrict__ phi, float* __restrict__ plo, int t)
{
    __shared__ short lds[24576];   // 48 KB
    if (blockIdx.x < 256) gemm_body<0>(blockIdx.x, lds, Ahi, Alo, Bx, Bh, phi, plo, t);
    else                  gemm_body<1>(blockIdx.x - 256, lds, Ahi, Alo, Bx, Bh, phi, plo, t);
}

// ================= new-path per-step update =================
__global__ __launch_bounds__(256) void update2(
    const float* __restrict__ phi, const float* __restrict__ plo,
    const float* __restrict__ b_ih, const float* __restrict__ b_hh,
    const int* __restrict__ lens,
    float* __restrict__ cbuf,       // [dir][2048][64] f32
    short* __restrict__ Bh,         // packed h hi/lo
    float* __restrict__ out, int t)
{
    int tid0 = blockIdx.x * 256 + threadIdx.x;
    for (int item = tid0; item < 262144; item += 65536) {
        int b = item & 63, k = (item >> 6) & 2047, dir = item >> 17;
        float g[4];
#pragma unroll
        for (int gg = 0; gg < 4; ++gg) {
            int row = gg * 2048 + k;
            float v = 0.f;
#pragma unroll
            for (int s = 0; s < 4; ++s) v += phi[((size_t)s * 8192 + row) * 128 + dir * 64 + b];
#pragma unroll
            for (int s = 0; s < 4; ++s) v += plo[((size_t)s * 8192 + row) * 128 + dir * 64 + b];
            g[gg] = v + b_ih[row] + b_hh[row];
        }
        float iv = sigm(g[0]);
        float fv = sigm(g[1]);
        float gv = tanhf(g[2]);
        float ov = sigm(g[3]);
        size_t cidx = ((size_t)dir * 2048 + k) * 64 + b;
        float c = fv * cbuf[cidx] + iv * gv;
        cbuf[cidx] = c;
        float h = ov * tanhf(c);

        int kk = k & 31, ksh = k >> 5;
        int jj = kk & 7, ll = (kk >> 3) * 16 + (b & 15), sub = b >> 4;
        int pingW = (t + 1) & 1;
        size_t baseh = (size_t)pingW * BHPING + ((size_t)ksh * 16 + (dir * 2) * 4 + sub) * 512 + ll * 8 + jj;
        size_t basel = (size_t)pingW * BHPING + ((size_t)ksh * 16 + (dir * 2 + 1) * 4 + sub) * 512 + ll * 8 + jj;
        unsigned hb = f2bf(h);
        Bh[baseh] = (short)hb;
        Bh[basel] = (short)f2bf(h - bf2f(hb));

        if (dir == 0) { if (t == lens[b] - 1) out[(size_t)b * 4096 + k] = h; }
        else          { if (t == 127)         out[(size_t)b * 4096 + 2048 + k] = h; }
    }
}

// ======================================================================
// ================= round-2 fallback path (proven, ~102 MiB) ===========
// ======================================================================
#define R2K1    2368
#define R2EPAD  304
#define R2HOFF  304
#define R2HEND  2352
#define R2SEGSTEPS 74
#define R2REALSTEPS 222
#define R2SPLITSTEPS 56

__global__ void init_ws2(short* __restrict__ hb, float* __restrict__ cb,
                         short* __restrict__ zer) {
    const int nH = 2 * 2 * 2 * 64 * 2048;
    const int nC = 2 * 2048 * 64;
    int stride = gridDim.x * blockDim.x;
    int i = blockIdx.x * blockDim.x + threadIdx.x;
    for (int idx = i; idx < nH; idx += stride) hb[idx] = 0;
    for (int idx = i; idx < nC; idx += stride) cb[idx] = 0.f;
    for (int idx = i; idx < 128; idx += stride) zer[idx] = 0;
}

__global__ void conv_w(const float* __restrict__ Wih, const float* __restrict__ Whh,
                       short* __restrict__ whi, short* __restrict__ wlo) {
    int idx = blockIdx.x * blockDim.x + threadIdx.x;
    const int total = 8192 * R2K1;
    if (idx >= total) return;
    int j = idx / R2K1;
    int col = idx - j * R2K1;
    float w = 0.f;
    if (col < E_) w = Wih[(size_t)j * E_ + col];
    else if (col >= R2HOFF && col < R2HEND) w = Whh[(size_t)j * H_ + (col - R2HOFF)];
    unsigned hb = f2bf(w);
    whi[idx] = (short)hb;
    wlo[idx] = (short)f2bf(w - bf2f(hb));
}

__global__ void conv_x(const int* __restrict__ tokens, const float* __restrict__ embed,
                       short* __restrict__ xhi, short* __restrict__ xlo) {
    int idx = blockIdx.x * blockDim.x + threadIdx.x;
    const int total = T_ * B_ * R2EPAD;
    if (idx >= total) return;
    int t = idx / (B_ * R2EPAD);
    int r = idx - t * (B_ * R2EPAD);
    int bb = r / R2EPAD;
    int e = r - bb * R2EPAD;
    float v = 0.f;
    if (e < E_) {
        int tok = tokens[t * B_ + bb];
        v = embed[(size_t)tok * E_ + e];
    }
    unsigned hb = f2bf(v);
    xhi[idx] = (short)hb;
    xlo[idx] = (short)f2bf(v - bf2f(hb));
}

__global__ __launch_bounds__(512) void gemm_partial(
    const short* __restrict__ Whi, const short* __restrict__ Wlo,
    const short* __restrict__ xhi, const short* __restrict__ xlo,
    const short* __restrict__ hbuf,
    const short* __restrict__ zeros,
    float* __restrict__ pbuf, int t)
{
    __shared__ short As[2][8192];
    __shared__ short Bs[2][2048];

    const int bx  = blockIdx.x;
    const int s   = bx & 3;
    const int kt  = (bx >> 2) & 31;
    const int dir = bx >> 7;
    const int tid = threadIdx.x;
    const int w   = tid >> 6;
    const int l   = tid & 63;
    const int ping = t & 1;
    const int xt   = dir ? (T_ - 1 - t) : t;

    int jA[2], cA[2];
#pragma unroll
    for (int q = 0; q < 2; ++q) {
        int idx = (w * 2 + q) * 64 + l;
        cA[q] = idx >> 8;
        int row = idx & 255;
        jA[q] = (row >> 6) * 2048 + kt * 64 + (row & 63);
    }
    int cB = 0, bB = 0;
    if (w < 4) { int idx = w * 64 + l; cB = idx >> 6; bB = idx & 63; }

    const int lhi = l >> 4, llo = l & 15;
    const int rowbase = (w >> 1) * 64 + (w & 1) * 32;

    float4v acc[2][4];
#pragma unroll
    for (int a = 0; a < 2; ++a)
#pragma unroll
        for (int b = 0; b < 4; ++b) acc[a][b] = (float4v){0.f, 0.f, 0.f, 0.f};

    auto stage = [&](int g, int buf) {
        const bool dummy = (g >= R2REALSTEPS);
        const int seg = dummy ? 2 : g / R2SEGSTEPS;
        const int ss  = dummy ? 0 : g - seg * R2SEGSTEPS;
        const int kbase = ss * 32;
        const short* Wsel = (seg < 2) ? Whi : Wlo;
        const int hl = (seg == 1) ? 1 : 0;
        const short* xsel = (seg == 1) ? xlo : xhi;
        const short* hsel = hbuf + (((size_t)ping * 2 + hl) * 2 + dir) * (64 * 2048);
#pragma unroll
        for (int q = 0; q < 2; ++q) {
            const short* src = Wsel + (size_t)jA[q] * R2K1 + kbase + 8 * cA[q];
            gl_lds16(src, &As[buf][(w * 2 + q) * 64 * 8]);
        }
        if (w < 4) {
            int row8 = kbase + 8 * cB;
            const short* src;
            if (dummy || row8 >= R2HEND) src = zeros;
            else if (row8 < R2EPAD)      src = xsel + ((size_t)xt * 64 + bB) * R2EPAD + row8;
            else                         src = hsel + (size_t)bB * 2048 + (row8 - R2HOFF);
            gl_lds16(src, &Bs[buf][w * 64 * 8]);
        }
    };

    const int g0 = s * R2SPLITSTEPS;
    stage(g0, 0);

    for (int it = 0; it < R2SPLITSTEPS; ++it) {
        const int buf = it & 1;
        if (it + 1 < R2SPLITSTEPS) stage(g0 + it + 1, buf ^ 1);
        __syncthreads();
        short8 a0 = *(const short8*)&As[buf][(lhi * 256 + rowbase + llo) * 8];
        short8 a1 = *(const short8*)&As[buf][(lhi * 256 + rowbase + 16 + llo) * 8];
        short8 b0 = *(const short8*)&Bs[buf][(lhi * 64 + llo) * 8];
        short8 b1 = *(const short8*)&Bs[buf][(lhi * 64 + 16 + llo) * 8];
        short8 b2 = *(const short8*)&Bs[buf][(lhi * 64 + 32 + llo) * 8];
        short8 b3 = *(const short8*)&Bs[buf][(lhi * 64 + 48 + llo) * 8];
        acc[0][0] = __builtin_amdgcn_mfma_f32_16x16x32_bf16(a0, b0, acc[0][0], 0, 0, 0);
        acc[0][1] = __builtin_amdgcn_mfma_f32_16x16x32_bf16(a0, b1, acc[0][1], 0, 0, 0);
        acc[0][2] = __builtin_amdgcn_mfma_f32_16x16x32_bf16(a0, b2, acc[0][2], 0, 0, 0);
        acc[0][3] = __builtin_amdgcn_mfma_f32_16x16x32_bf16(a0, b3, acc[0][3], 0, 0, 0);
        acc[1][0] = __builtin_amdgcn_mfma_f32_16x16x32_bf16(a1, b0, acc[1][0], 0, 0, 0);
        acc[1][1] = __builtin_amdgcn_mfma_f32_16x16x32_bf16(a1, b1, acc[1][1], 0, 0, 0);
        acc[1][2] = __builtin_amdgcn_mfma_f32_16x16x32_bf16(a1, b2, acc[1][2], 0, 0, 0);
        acc[1][3] = __builtin_amdgcn_mfma_f32_16x16x32_bf16(a1, b3, acc[1][3], 0, 0, 0);
        __syncthreads();
    }

    float* pb = pbuf + (((size_t)(dir * 32 + kt) * 4 + s) * 256) * 64;
#pragma unroll
    for (int qm = 0; qm < 2; ++qm)
#pragma unroll
        for (int nb = 0; nb < 4; ++nb)
#pragma unroll
            for (int r = 0; r < 4; ++r) {
                int row = rowbase + qm * 16 + lhi * 4 + r;
                int col = nb * 16 + llo;
                pb[row * 64 + col] = acc[qm][nb][r];
            }
}

__global__ __launch_bounds__(256) void lstm_update(
    const float* __restrict__ pbuf,
    const float* __restrict__ b_ih, const float* __restrict__ b_hh,
    const int* __restrict__ lens,
    float* __restrict__ cbuf,
    short* __restrict__ hbuf,
    float* __restrict__ out, int t)
{
    const int bx = blockIdx.x;
    const int kt = bx & 31, dir = bx >> 5;
    const float* pb = pbuf + (size_t)(dir * 32 + kt) * 4 * 256 * 64;
    const int ping = (t + 1) & 1;

    for (int idx = threadIdx.x; idx < 4096; idx += 256) {
        const int q = idx >> 6, bb = idx & 63;
        const int k = kt * 64 + q;
        float gv[4];
#pragma unroll
        for (int gg = 0; gg < 4; ++gg) {
            const int r = gg * 64 + q;
            float v = 0.f;
#pragma unroll
            for (int s2 = 0; s2 < 4; ++s2) v += pb[(s2 * 256 + r) * 64 + bb];
            const int j = gg * 2048 + k;
            gv[gg] = v + b_ih[j] + b_hh[j];
        }
        const float iv = sigm(gv[0]);
        const float fv = sigm(gv[1]);
        const float g2 = tanhf(gv[2]);
        const float ov = sigm(gv[3]);
        const size_t cidx = ((size_t)dir * 2048 + k) * 64 + bb;
        const float c = fv * cbuf[cidx] + iv * g2;
        cbuf[cidx] = c;
        const float h = ov * tanhf(c);

        const unsigned hb = f2bf(h);
        const float hhi = bf2f(hb);
        const unsigned lb = f2bf(h - hhi);
        const size_t basehi = (((size_t)ping * 2 + 0) * 2 + dir) * (64 * 2048);
        const size_t baselo = (((size_t)ping * 2 + 1) * 2 + dir) * (64 * 2048);
        hbuf[basehi + (size_t)bb * 2048 + k] = (short)hb;
        hbuf[baselo + (size_t)bb * 2048 + k] = (short)lb;

        if (dir == 0) {
            if (t == lens[bb] - 1) out[(size_t)bb * (2 * H_) + k] = h;
        } else {
            if (t == T_ - 1) out[(size_t)bb * (2 * H_) + H_ + k] = h;
        }
    }
}

// ================= round-1 last-resort path =================
__global__ void init_state(float* __restrict__ hbuf, float* __restrict__ cbuf) {
    int n_h = 2 * 2 * H_ * B_;
    int n_c = 2 * H_ * B_;
    int stride = gridDim.x * blockDim.x;
    int i = blockIdx.x * blockDim.x + threadIdx.x;
    for (int idx = i; idx < n_h; idx += stride) hbuf[idx] = 0.f;
    for (int idx = i; idx < n_c; idx += stride) cbuf[idx] = 0.f;
}

__global__ void gather_x(const int* __restrict__ tokens, const float* __restrict__ embed,
                         float* __restrict__ x_t) {
    int idx = blockIdx.x * blockDim.x + threadIdx.x;
    int total = T_ * E_ * B_;
    if (idx >= total) return;
    int b = idx % B_;
    int r = idx / B_;
    int e = r % E_;
    int t = r / E_;
    int tok = tokens[t * B_ + b];
    x_t[idx] = embed[tok * E_ + e];
}

__global__ __launch_bounds__(256) void lstm_step(
    const float* __restrict__ x_t, const float* __restrict__ W_ih,
    const float* __restrict__ W_hh, const float* __restrict__ b_ih,
    const float* __restrict__ b_hh, const int* __restrict__ lens,
    const float* __restrict__ h_in, float* __restrict__ h_out,
    float* __restrict__ cbuf, float* __restrict__ out, int t)
{
    const int dir = blockIdx.x >> 8;
    const int kblk = blockIdx.x & 255;
    const int bpair = threadIdx.x & 31;
    const int kloc = threadIdx.x >> 5;
    const int k = kblk * 8 + kloc;
    const int b0 = bpair * 2;
    const int xt = dir ? (T_ - 1 - t) : t;
    const float* xrow = x_t + (size_t)xt * E_ * B_;
    const float* hrow = h_in + (size_t)dir * H_ * B_;
    float a0x = 0.f, a0y = 0.f, a1x = 0.f, a1y = 0.f;
    float a2x = 0.f, a2y = 0.f, a3x = 0.f, a3y = 0.f;
    {
        const float* w0 = W_ih + (size_t)(0 * H_ + k) * E_;
        const float* w1 = W_ih + (size_t)(1 * H_ + k) * E_;
        const float* w2 = W_ih + (size_t)(2 * H_ + k) * E_;
        const float* w3 = W_ih + (size_t)(3 * H_ + k) * E_;
#pragma unroll 4
        for (int kk = 0; kk < E_; ++kk) {
            float2 xv = *(const float2*)(xrow + kk * B_ + b0);
            float c0 = w0[kk], c1 = w1[kk], c2 = w2[kk], c3 = w3[kk];
            a0x += xv.x * c0; a0y += xv.y * c0;
            a1x += xv.x * c1; a1y += xv.y * c1;
            a2x += xv.x * c2; a2y += xv.y * c2;
            a3x += xv.x * c3; a3y += xv.y * c3;
        }
    }
    {
        const float* w0 = W_hh + (size_t)(0 * H_ + k) * H_;
        const float* w1 = W_hh + (size_t)(1 * H_ + k) * H_;
        const float* w2 = W_hh + (size_t)(2 * H_ + k) * H_;
        const float* w3 = W_hh + (size_t)(3 * H_ + k) * H_;
#pragma unroll 4
        for (int kk = 0; kk < H_; ++kk) {
            float2 hv = *(const float2*)(hrow + kk * B_ + b0);
            float c0 = w0[kk], c1 = w1[kk], c2 = w2[kk], c3 = w3[kk];
            a0x += hv.x * c0; a0y += hv.y * c0;
            a1x += hv.x * c1; a1y += hv.y * c1;
            a2x += hv.x * c2; a2y += hv.y * c2;
            a3x += hv.x * c3; a3y += hv.y * c3;
        }
    }
    const int j0 = 0 * H_ + k, j1 = 1 * H_ + k, j2 = 2 * H_ + k, j3 = 3 * H_ + k;
    const float bi = b_ih[j0] + b_hh[j0];
    const float bf = b_ih[j1] + b_hh[j1];
    const float bg = b_ih[j2] + b_hh[j2];
    const float bo = b_ih[j3] + b_hh[j3];
    float* cdir = cbuf + (size_t)dir * H_ * B_;
    float* hdir = h_out + (size_t)dir * H_ * B_;
#pragma unroll
    for (int s = 0; s < 2; ++s) {
        const int b = b0 + s;
        const float ai = (s == 0) ? a0x : a0y;
        const float af = (s == 0) ? a1x : a1y;
        const float ag = (s == 0) ? a2x : a2y;
        const float ao = (s == 0) ? a3x : a3y;
        const float iv = sigm(ai + bi);
        const float fv = sigm(af + bf);
        const float gv = tanhf(ag + bg);
        const float ov = sigm(ao + bo);
        const int sidx = k * B_ + b;
        const float c_old = cdir[sidx];
        const float c_new = fv * c_old + iv * gv;
        cdir[sidx] = c_new;
        const float h_new = ov * tanhf(c_new);
        hdir[sidx] = h_new;
        if (dir == 0) {
            if (t == lens[b] - 1) out[(size_t)b * (2 * H_) + k] = h_new;
        } else {
            if (t == T_ - 1) out[(size_t)b * (2 * H_) + H_ + k] = h_new;
        }
    }
}

// ================= launch =================
extern "C" void kernel_launch(void* const* d_in, const int* in_sizes, int n_in,
                              void* d_out, int out_size, void* d_ws, size_t ws_size,
                              hipStream_t stream) {
    const int*   tokens = (const int*)d_in[0];
    const int*   lens   = (const int*)d_in[1];
    const float* embed  = (const float*)d_in[2];
    const float* W_ih   = (const float*)d_in[3];
    const float* W_hh   = (const float*)d_in[4];
    const float* b_ih   = (const float*)d_in[5];
    const float* b_hh   = (const float*)d_in[6];
    float* out = (float*)d_out;

    // ---- new-path layout ----
    short* Ahi = (short*)d_ws;
    short* Alo = Ahi + APELEMS;
    short* BxP = Alo + APELEMS;
    short* BhP = BxP + BXELEMS;
    float* cb2n = (float*)(BhP + 2 * BHPING);
    float* phi  = cb2n + 262144;
    float* plo  = phi + 4194304;
    const size_t req_new = (size_t)((char*)(plo + 4194304) - (char*)d_ws);

    // ---- r2 layout ----
    const size_t SZ_W  = (size_t)8192 * R2K1;
    const size_t SZ_X  = (size_t)T_ * B_ * R2EPAD;
    const size_t SZ_HB = (size_t)2 * 2 * 2 * 64 * 2048;
    const size_t SZ_CB = (size_t)2 * 2048 * 64;
    const size_t SZ_PB = (size_t)64 * 4 * 256 * 64;
    short* Whi2  = (short*)d_ws;
    short* Wlo2  = Whi2 + SZ_W;
    short* xhiB = Wlo2 + SZ_W;
    short* xloB = xhiB + SZ_X;
    short* hb2  = xloB + SZ_X;
    short* zer  = hb2 + SZ_HB;
    float* cb2  = (float*)(zer + 128);
    float* pbuf = cb2 + SZ_CB;
    const size_t req_r2 = (size_t)((char*)(pbuf + SZ_PB) - (char*)d_ws);

    if (ws_size >= req_new) {
        init2<<<512, 256, 0, stream>>>(BhP, cb2n);
        pack_w<<<(int)((APELEMS + 255) / 256), 256, 0, stream>>>(W_ih, W_hh, Ahi, Alo);
        pack_x<<<(int)((BXELEMS + 255) / 256), 256, 0, stream>>>(tokens, embed, BxP);
        for (int t = 0; t < T_; ++t) {
            gemm_step<<<512, 512, 0, stream>>>(Ahi, Alo, BxP, BhP, phi, plo, t);
            update2<<<256, 256, 0, stream>>>(phi, plo, b_ih, b_hh, lens, cb2n, BhP, out, t);
        }
    } else if (ws_size >= req_r2) {
        init_ws2<<<1024, 256, 0, stream>>>(hb2, cb2, zer);
        {
            int total = 8192 * R2K1;
            conv_w<<<(total + 255) / 256, 256, 0, stream>>>(W_ih, W_hh, Whi2, Wlo2);
        }
        {
            int total = T_ * B_ * R2EPAD;
            conv_x<<<(total + 255) / 256, 256, 0, stream>>>(tokens, embed, xhiB, xloB);
        }
        for (int t = 0; t < T_; ++t) {
            gemm_partial<<<256, 512, 0, stream>>>(Whi2, Wlo2, xhiB, xloB, hb2, zer, pbuf, t);
            lstm_update<<<64, 256, 0, stream>>>(pbuf, b_ih, b_hh, lens, cb2, hb2, out, t);
        }
    } else {
        float* ws   = (float*)d_ws;
        float* x_t  = ws;
        float* hbuf = x_t + (size_t)T_ * E_ * B_;
        float* cbuf = hbuf + (size_t)2 * 2 * H_ * B_;
        init_state<<<256, 256, 0, stream>>>(hbuf, cbuf);
        {
            int total = T_ * E_ * B_;
            gather_x<<<(total + 255) / 256, 256, 0, stream>>>(tokens, embed, x_t);
        }
        for (int t = 0; t < T_; ++t) {
            const float* h_in  = hbuf + (size_t)(t & 1) * 2 * H_ * B_;
            float*       h_out = hbuf + (size_t)((t + 1) & 1) * 2 * H_ * B_;
            lstm_step<<<512, 256, 0, stream>>>(x_t, W_ih, W_hh, b_ih, b_hh, lens,
                                               h_in, h_out, cbuf, out, t);
        }
    }
}

// Round 4
// 4465.134 us; speedup vs baseline: 7.6188x; 1.1359x over previous
//
#include <hip/hip_runtime.h>
#include <math.h>

#define T_ 128
#define B_ 64
#define E_ 300
#define H_ 2048

// ======== new-path geometry ========
// K layout: [0,300) x | [300,320) zero-pad | [320,2368) h   -> K1 = 2368 = 74 ksteps of 32
#define K1   2368
#define XKS  10      // x ksteps (320/32)
#define NKS  74      // total ksteps
#define APELEMS 19398656ull   // 8192 * 2368, per weight matrix (frag-major packed)
#define BXELEMS 5242880ull    // 128 t * 10 ks * 2 hl * 4 nf * 64 l * 8 j
#define BHPING  524288ull     // 64 ks * 16 nf * 64 l * 8 j   (shorts per ping)

typedef __attribute__((ext_vector_type(8))) short short8;
typedef __attribute__((ext_vector_type(4))) float float4v;

__device__ __forceinline__ unsigned f2bf(float f) {
    unsigned u = __float_as_uint(f);
    return (u + 0x7FFFu + ((u >> 16) & 1u)) >> 16;
}
__device__ __forceinline__ float bf2f(unsigned b) { return __uint_as_float(b << 16); }

__device__ __forceinline__ void gl_lds16(const void* g, void* l) {
    __builtin_amdgcn_global_load_lds(
        (const __attribute__((address_space(1))) unsigned int*)g,
        (__attribute__((address_space(3))) unsigned int*)l, 16, 0, 0);
}

__device__ __forceinline__ float sigm(float x) { return 1.f / (1.f + expf(-x)); }

// ================= new-path prologue =================

__global__ void init2(short* __restrict__ Bh, float* __restrict__ cb) {
    const int nB = 2 * (int)BHPING;     // shorts
    const int nC = 2 * 2048 * 64;       // floats
    int stride = gridDim.x * blockDim.x;
    int i = blockIdx.x * blockDim.x + threadIdx.x;
    for (int idx = i; idx < nB; idx += stride) Bh[idx] = 0;
    for (int idx = i; idx < nC; idx += stride) cb[idx] = 0.f;
}

// frag-major packed weights: [rb(64)][ks(74)][mf(8)][l(64)][j(8)]
// element = W[row = rb*128+mf*16+(l&15)][kr = ks*32+(l>>4)*8+j]
__global__ void pack_w(const float* __restrict__ Wih, const float* __restrict__ Whh,
                       short* __restrict__ Ahi, short* __restrict__ Alo) {
    long long idx = (long long)blockIdx.x * blockDim.x + threadIdx.x;
    if (idx >= (long long)APELEMS) return;
    int j  = (int)(idx & 7);
    int l  = (int)((idx >> 3) & 63);
    int mf = (int)((idx >> 9) & 7);
    int rest = (int)(idx >> 12);
    int ks = rest % 74;
    int rb = rest / 74;
    int row = rb * 128 + mf * 16 + (l & 15);
    int kr  = ks * 32 + (l >> 4) * 8 + j;
    float wv = 0.f;
    if (kr < 300)       wv = Wih[(size_t)row * 300 + kr];
    else if (kr >= 320) wv = Whh[(size_t)row * 2048 + (kr - 320)];
    unsigned hb = f2bf(wv);
    Ahi[idx] = (short)hb;
    Alo[idx] = (short)f2bf(wv - bf2f(hb));
}

// packed x: [t(128)][ks(10)][hl(2)][nf4(4)][l(64)][j(8)]
// col b = nf4*16+(l&15); kr = ks*32+(l>>4)*8+j
__global__ void pack_x(const int* __restrict__ tokens, const float* __restrict__ embed,
                       short* __restrict__ Bx) {
    long long idx = (long long)blockIdx.x * blockDim.x + threadIdx.x;
    if (idx >= (long long)BXELEMS) return;
    int j   = (int)(idx & 7);
    int l   = (int)((idx >> 3) & 63);
    int nf4 = (int)((idx >> 9) & 3);
    int hl  = (int)((idx >> 11) & 1);
    int rest = (int)(idx >> 12);
    int ks = rest % 10;
    int tt = rest / 10;
    int b  = nf4 * 16 + (l & 15);
    int kr = ks * 32 + (l >> 4) * 8 + j;
    float v = 0.f;
    if (kr < 300) {
        int tok = tokens[tt * 64 + b];
        v = embed[(size_t)tok * 300 + kr];
    }
    unsigned hb = f2bf(v);
    Bx[idx] = hl ? (short)f2bf(v - bf2f(hb)) : (short)hb;
}

// ================= new-path per-step GEMM =================
// TYPE 0 (Whi): 256 blocks = rb(64)*s(4); M=128, N=256 (cg: d0hi,d0lo,d1hi,d1lo)
//               wavegrid 2(M)x4(N); epilogue sums hi+lo col pairs -> phi[s][8192][128]
// TYPE 1 (Wlo): 256 blocks; M=128, N=128 (cg: d0hi,d1hi); wavegrid 4x2 -> plo[s][8192][128]
//
// K-loop: 3-buffer counted-vmcnt pipeline. Per stage, each thread issues a FIXED
// load count (TYPE0: 3, TYPE1: 2), so s_waitcnt vmcnt(3)/(2) at the per-iteration
// barrier waits exactly for tile t+1 while tile t+2 stays in flight across the
// barrier. Tail uses uniform clamped over-fetch to keep counts exact.
template<int TYPE>
__device__ __forceinline__ void gemm_body(
    int bb, short* lds,
    const short* __restrict__ Ahi, const short* __restrict__ Alo,
    const short* __restrict__ Bx, const short* __restrict__ Bh,
    float* __restrict__ phi, float* __restrict__ plo, int t)
{
    const int rb = bb >> 2, s = bb & 3;
    const int tid = (int)threadIdx.x;
    const int w = tid >> 6, l = tid & 63;
    const int ping = t & 1;
    constexpr int MF = TYPE ? 2 : 4;
    const short* Ap = TYPE ? Alo : Ahi;

    const int ks0 = (74 * s) >> 2, ks1 = (74 * (s + 1)) >> 2;
    const int nks = ks1 - ks0;

    float4v acc[MF][4];
#pragma unroll
    for (int i = 0; i < MF; ++i)
#pragma unroll
        for (int n = 0; n < 4; ++n) acc[i][n] = (float4v){0.f, 0.f, 0.f, 0.f};

    auto stage = [&](int ks, int buf) {
        short* As = lds + buf * 12288;
        short* Bs = As + 4096;
        // A: 512 chunks of 16B, linear
        {
            const short* src = Ap + ((size_t)(rb * 74 + ks) * 512 + tid) * 8;
            gl_lds16(src, As + tid * 8);
        }
        // B
        const int NB = TYPE ? 1 : 2;
#pragma unroll
        for (int q = 0; q < NB; ++q) {
            int c = q * 512 + tid;
            int nt = c >> 6, ll = c & 63;
            int dsel, hl, nf;
            if (TYPE) { dsel = nt >> 2; hl = 0; nf = dsel * 8 + (nt & 3); }
            else      { nf = nt; dsel = nf >> 3; hl = (nf >> 2) & 1; }
            const short* src;
            if (ks < XKS) {
                int xt = dsel ? (127 - t) : t;
                src = Bx + (((size_t)(xt * 10 + ks) * 2 + hl) * 4 + (nf & 3)) * 512 + ll * 8;
            } else {
                src = Bh + (size_t)ping * BHPING + ((size_t)(ks - XKS) * 16 + nf) * 512 + ll * 8;
            }
            gl_lds16(src, Bs + c * 8);
        }
    };

    const int wm = TYPE ? (w >> 1) : (w >> 2);
    const int wn = TYPE ? (w & 1) : (w & 3);

    // prologue: tiles 0,1 staged; wait tile0 landed (leave tile1 in flight)
    stage(ks0, 0);
    stage(ks0 + 1, 1);
    if constexpr (TYPE) { asm volatile("s_waitcnt vmcnt(2)" ::: "memory"); }
    else                { asm volatile("s_waitcnt vmcnt(3)" ::: "memory"); }
    __builtin_amdgcn_s_barrier();
    __builtin_amdgcn_sched_barrier(0);

    for (int it = 0; it < nks; ++it) {
        const int buf = it % 3;
        int pre = it + 2; if (pre > nks - 1) pre = nks - 1;   // clamped over-fetch
        stage(ks0 + pre, (it + 2) % 3);

        short* As = lds + buf * 12288;
        short* Bs = As + 4096;
        short8 a[MF], b[4];
#pragma unroll
        for (int i = 0; i < MF; ++i)
            a[i] = *(const short8*)(As + ((wm * MF + i) * 64 + l) * 8);
#pragma unroll
        for (int n = 0; n < 4; ++n)
            b[n] = *(const short8*)(Bs + ((wn * 4 + n) * 64 + l) * 8);
#pragma unroll
        for (int i = 0; i < MF; ++i)
#pragma unroll
            for (int n = 0; n < 4; ++n)
                acc[i][n] = __builtin_amdgcn_mfma_f32_16x16x32_bf16(a[i], b[n], acc[i][n], 0, 0, 0);

        // wait tile it+1 landed; tile it+2 stays in flight across the barrier
        if constexpr (TYPE) { asm volatile("s_waitcnt vmcnt(2)" ::: "memory"); }
        else                { asm volatile("s_waitcnt vmcnt(3)" ::: "memory"); }
        __builtin_amdgcn_s_barrier();
        __builtin_amdgcn_sched_barrier(0);
    }

    // drain stray clamped prefetches before LDS reuse / endpgm
    asm volatile("s_waitcnt vmcnt(0)" ::: "memory");
    __builtin_amdgcn_s_barrier();
    __builtin_amdgcn_sched_barrier(0);

    if (TYPE == 0) {
        // reduce col pairs (wn 0<-1 for d0, 2<-3 for d1) via LDS, then write phi
        float* red = (float*)lds;   // 32KB scratch
#pragma unroll
        for (int rnd = 0; rnd < 2; ++rnd) {
            __syncthreads();
            if (wn == rnd * 2 + 1) {
#pragma unroll
                for (int i = 0; i < 4; ++i)
#pragma unroll
                    for (int n = 0; n < 4; ++n)
                        *(float4v*)(red + ((wm * 16 + i * 4 + n) * 64 + l) * 4) = acc[i][n];
            }
            __syncthreads();
            if (wn == rnd * 2) {
#pragma unroll
                for (int i = 0; i < 4; ++i)
#pragma unroll
                    for (int n = 0; n < 4; ++n) {
                        float4v v = *(const float4v*)(red + ((wm * 16 + i * 4 + n) * 64 + l) * 4);
                        acc[i][n] += v;
                    }
            }
        }
        if (!(wn & 1)) {
            const int d = wn >> 1;
#pragma unroll
            for (int i = 0; i < 4; ++i)
#pragma unroll
                for (int n = 0; n < 4; ++n)
#pragma unroll
                    for (int r = 0; r < 4; ++r) {
                        int row = rb * 128 + wm * 64 + i * 16 + (l >> 4) * 4 + r;
                        int col = d * 64 + n * 16 + (l & 15);
                        phi[((size_t)s * 8192 + row) * 128 + col] = acc[i][n][r];
                    }
        }
    } else {
#pragma unroll
        for (int i = 0; i < 2; ++i)
#pragma unroll
            for (int n = 0; n < 4; ++n)
#pragma unroll
                for (int r = 0; r < 4; ++r) {
                    int nt = wn * 4 + n;
                    int row = rb * 128 + (wm * 2 + i) * 16 + (l >> 4) * 4 + r;
                    int col = (nt >> 2) * 64 + (nt & 3) * 16 + (l & 15);
                    plo[((size_t)s * 8192 + row) * 128 + col] = acc[i][n][r];
                }
    }
}

__global__ __launch_bounds__(512, 4) void gemm_step(
    const short* __restrict__ Ahi, const short* __restrict__ Alo,
    const short* __restrict__ Bx, const short* __restrict__ Bh,
    float* __restrict__ phi, float* __restrict__ plo, int t)
{
    __shared__ short lds[36864];   // 3 bufs x 24KB = 72 KB
    if (blockIdx.x < 256) gemm_body<0>(blockIdx.x, lds, Ahi, Alo, Bx, Bh, phi, plo, t);
    else                  gemm_body<1>(blockIdx.x - 256, lds, Ahi, Alo, Bx, Bh, phi, plo, t);
}

// ================= new-path per-step update =================
__global__ __launch_bounds__(256) void update2(
    const float* __restrict__ phi, const float* __restrict__ plo,
    const float* __restrict__ b_ih, const float* __restrict__ b_hh,
    const int* __restrict__ lens,
    float* __restrict__ cbuf,       // [dir][2048][64] f32
    short* __restrict__ Bh,         // packed h hi/lo
    float* __restrict__ out, int t)
{
    int tid0 = blockIdx.x * 256 + threadIdx.x;
    for (int item = tid0; item < 262144; item += 65536) {
        int b = item & 63, k = (item >> 6) & 2047, dir = item >> 17;
        float g[4];
#pragma unroll
        for (int gg = 0; gg < 4; ++gg) {
            int row = gg * 2048 + k;
            float v = 0.f;
#pragma unroll
            for (int s = 0; s < 4; ++s) v += phi[((size_t)s * 8192 + row) * 128 + dir * 64 + b];
#pragma unroll
            for (int s = 0; s < 4; ++s) v += plo[((size_t)s * 8192 + row) * 128 + dir * 64 + b];
            g[gg] = v + b_ih[row] + b_hh[row];
        }
        float iv = sigm(g[0]);
        float fv = sigm(g[1]);
        float gv = tanhf(g[2]);
        float ov = sigm(g[3]);
        size_t cidx = ((size_t)dir * 2048 + k) * 64 + b;
        float c = fv * cbuf[cidx] + iv * gv;
        cbuf[cidx] = c;
        float h = ov * tanhf(c);

        int kk = k & 31, ksh = k >> 5;
        int jj = kk & 7, ll = (kk >> 3) * 16 + (b & 15), sub = b >> 4;
        int pingW = (t + 1) & 1;
        size_t baseh = (size_t)pingW * BHPING + ((size_t)ksh * 16 + (dir * 2) * 4 + sub) * 512 + ll * 8 + jj;
        size_t basel = (size_t)pingW * BHPING + ((size_t)ksh * 16 + (dir * 2 + 1) * 4 + sub) * 512 + ll * 8 + jj;
        unsigned hb = f2bf(h);
        Bh[baseh] = (short)hb;
        Bh[basel] = (short)f2bf(h - bf2f(hb));

        if (dir == 0) { if (t == lens[b] - 1) out[(size_t)b * 4096 + k] = h; }
        else          { if (t == 127)         out[(size_t)b * 4096 + 2048 + k] = h; }
    }
}

// ======================================================================
// ================= round-2 fallback path (proven, ~102 MiB) ===========
// ======================================================================
#define R2K1    2368
#define R2EPAD  304
#define R2HOFF  304
#define R2HEND  2352
#define R2SEGSTEPS 74
#define R2REALSTEPS 222
#define R2SPLITSTEPS 56

__global__ void init_ws2(short* __restrict__ hb, float* __restrict__ cb,
                         short* __restrict__ zer) {
    const int nH = 2 * 2 * 2 * 64 * 2048;
    const int nC = 2 * 2048 * 64;
    int stride = gridDim.x * blockDim.x;
    int i = blockIdx.x * blockDim.x + threadIdx.x;
    for (int idx = i; idx < nH; idx += stride) hb[idx] = 0;
    for (int idx = i; idx < nC; idx += stride) cb[idx] = 0.f;
    for (int idx = i; idx < 128; idx += stride) zer[idx] = 0;
}

__global__ void conv_w(const float* __restrict__ Wih, const float* __restrict__ Whh,
                       short* __restrict__ whi, short* __restrict__ wlo) {
    int idx = blockIdx.x * blockDim.x + threadIdx.x;
    const int total = 8192 * R2K1;
    if (idx >= total) return;
    int j = idx / R2K1;
    int col = idx - j * R2K1;
    float w = 0.f;
    if (col < E_) w = Wih[(size_t)j * E_ + col];
    else if (col >= R2HOFF && col < R2HEND) w = Whh[(size_t)j * H_ + (col - R2HOFF)];
    unsigned hb = f2bf(w);
    whi[idx] = (short)hb;
    wlo[idx] = (short)f2bf(w - bf2f(hb));
}

__global__ void conv_x(const int* __restrict__ tokens, const float* __restrict__ embed,
                       short* __restrict__ xhi, short* __restrict__ xlo) {
    int idx = blockIdx.x * blockDim.x + threadIdx.x;
    const int total = T_ * B_ * R2EPAD;
    if (idx >= total) return;
    int t = idx / (B_ * R2EPAD);
    int r = idx - t * (B_ * R2EPAD);
    int bb = r / R2EPAD;
    int e = r - bb * R2EPAD;
    float v = 0.f;
    if (e < E_) {
        int tok = tokens[t * B_ + bb];
        v = embed[(size_t)tok * E_ + e];
    }
    unsigned hb = f2bf(v);
    xhi[idx] = (short)hb;
    xlo[idx] = (short)f2bf(v - bf2f(hb));
}

__global__ __launch_bounds__(512) void gemm_partial(
    const short* __restrict__ Whi, const short* __restrict__ Wlo,
    const short* __restrict__ xhi, const short* __restrict__ xlo,
    const short* __restrict__ hbuf,
    const short* __restrict__ zeros,
    float* __restrict__ pbuf, int t)
{
    __shared__ short As[2][8192];
    __shared__ short Bs[2][2048];

    const int bx  = blockIdx.x;
    const int s   = bx & 3;
    const int kt  = (bx >> 2) & 31;
    const int dir = bx >> 7;
    const int tid = threadIdx.x;
    const int w   = tid >> 6;
    const int l   = tid & 63;
    const int ping = t & 1;
    const int xt   = dir ? (T_ - 1 - t) : t;

    int jA[2], cA[2];
#pragma unroll
    for (int q = 0; q < 2; ++q) {
        int idx = (w * 2 + q) * 64 + l;
        cA[q] = idx >> 8;
        int row = idx & 255;
        jA[q] = (row >> 6) * 2048 + kt * 64 + (row & 63);
    }
    int cB = 0, bB = 0;
    if (w < 4) { int idx = w * 64 + l; cB = idx >> 6; bB = idx & 63; }

    const int lhi = l >> 4, llo = l & 15;
    const int rowbase = (w >> 1) * 64 + (w & 1) * 32;

    float4v acc[2][4];
#pragma unroll
    for (int a = 0; a < 2; ++a)
#pragma unroll
        for (int b = 0; b < 4; ++b) acc[a][b] = (float4v){0.f, 0.f, 0.f, 0.f};

    auto stage = [&](int g, int buf) {
        const bool dummy = (g >= R2REALSTEPS);
        const int seg = dummy ? 2 : g / R2SEGSTEPS;
        const int ss  = dummy ? 0 : g - seg * R2SEGSTEPS;
        const int kbase = ss * 32;
        const short* Wsel = (seg < 2) ? Whi : Wlo;
        const int hl = (seg == 1) ? 1 : 0;
        const short* xsel = (seg == 1) ? xlo : xhi;
        const short* hsel = hbuf + (((size_t)ping * 2 + hl) * 2 + dir) * (64 * 2048);
#pragma unroll
        for (int q = 0; q < 2; ++q) {
            const short* src = Wsel + (size_t)jA[q] * R2K1 + kbase + 8 * cA[q];
            gl_lds16(src, &As[buf][(w * 2 + q) * 64 * 8]);
        }
        if (w < 4) {
            int row8 = kbase + 8 * cB;
            const short* src;
            if (dummy || row8 >= R2HEND) src = zeros;
            else if (row8 < R2EPAD)      src = xsel + ((size_t)xt * 64 + bB) * R2EPAD + row8;
            else                         src = hsel + (size_t)bB * 2048 + (row8 - R2HOFF);
            gl_lds16(src, &Bs[buf][w * 64 * 8]);
        }
    };

    const int g0 = s * R2SPLITSTEPS;
    stage(g0, 0);

    for (int it = 0; it < R2SPLITSTEPS; ++it) {
        const int buf = it & 1;
        if (it + 1 < R2SPLITSTEPS) stage(g0 + it + 1, buf ^ 1);
        __syncthreads();
        short8 a0 = *(const short8*)&As[buf][(lhi * 256 + rowbase + llo) * 8];
        short8 a1 = *(const short8*)&As[buf][(lhi * 256 + rowbase + 16 + llo) * 8];
        short8 b0 = *(const short8*)&Bs[buf][(lhi * 64 + llo) * 8];
        short8 b1 = *(const short8*)&Bs[buf][(lhi * 64 + 16 + llo) * 8];
        short8 b2 = *(const short8*)&Bs[buf][(lhi * 64 + 32 + llo) * 8];
        short8 b3 = *(const short8*)&Bs[buf][(lhi * 64 + 48 + llo) * 8];
        acc[0][0] = __builtin_amdgcn_mfma_f32_16x16x32_bf16(a0, b0, acc[0][0], 0, 0, 0);
        acc[0][1] = __builtin_amdgcn_mfma_f32_16x16x32_bf16(a0, b1, acc[0][1], 0, 0, 0);
        acc[0][2] = __builtin_amdgcn_mfma_f32_16x16x32_bf16(a0, b2, acc[0][2], 0, 0, 0);
        acc[0][3] = __builtin_amdgcn_mfma_f32_16x16x32_bf16(a0, b3, acc[0][3], 0, 0, 0);
        acc[1][0] = __builtin_amdgcn_mfma_f32_16x16x32_bf16(a1, b0, acc[1][0], 0, 0, 0);
        acc[1][1] = __builtin_amdgcn_mfma_f32_16x16x32_bf16(a1, b1, acc[1][1], 0, 0, 0);
        acc[1][2] = __builtin_amdgcn_mfma_f32_16x16x32_bf16(a1, b2, acc[1][2], 0, 0, 0);
        acc[1][3] = __builtin_amdgcn_mfma_f32_16x16x32_bf16(a1, b3, acc[1][3], 0, 0, 0);
        __syncthreads();
    }

    float* pb = pbuf + (((size_t)(dir * 32 + kt) * 4 + s) * 256) * 64;
#pragma unroll
    for (int qm = 0; qm < 2; ++qm)
#pragma unroll
        for (int nb = 0; nb < 4; ++nb)
#pragma unroll
            for (int r = 0; r < 4; ++r) {
                int row = rowbase + qm * 16 + lhi * 4 + r;
                int col = nb * 16 + llo;
                pb[row * 64 + col] = acc[qm][nb][r];
            }
}

__global__ __launch_bounds__(256) void lstm_update(
    const float* __restrict__ pbuf,
    const float* __restrict__ b_ih, const float* __restrict__ b_hh,
    const int* __restrict__ lens,
    float* __restrict__ cbuf,
    short* __restrict__ hbuf,
    float* __restrict__ out, int t)
{
    const int bx = blockIdx.x;
    const int kt = bx & 31, dir = bx >> 5;
    const float* pb = pbuf + (size_t)(dir * 32 + kt) * 4 * 256 * 64;
    const int ping = (t + 1) & 1;

    for (int idx = threadIdx.x; idx < 4096; idx += 256) {
        const int q = idx >> 6, bb = idx & 63;
        const int k = kt * 64 + q;
        float gv[4];
#pragma unroll
        for (int gg = 0; gg < 4; ++gg) {
            const int r = gg * 64 + q;
            float v = 0.f;
#pragma unroll
            for (int s2 = 0; s2 < 4; ++s2) v += pb[(s2 * 256 + r) * 64 + bb];
            const int j = gg * 2048 + k;
            gv[gg] = v + b_ih[j] + b_hh[j];
        }
        const float iv = sigm(gv[0]);
        const float fv = sigm(gv[1]);
        const float g2 = tanhf(gv[2]);
        const float ov = sigm(gv[3]);
        const size_t cidx = ((size_t)dir * 2048 + k) * 64 + bb;
        const float c = fv * cbuf[cidx] + iv * g2;
        cbuf[cidx] = c;
        const float h = ov * tanhf(c);

        const unsigned hb = f2bf(h);
        const float hhi = bf2f(hb);
        const unsigned lb = f2bf(h - hhi);
        const size_t basehi = (((size_t)ping * 2 + 0) * 2 + dir) * (64 * 2048);
        const size_t baselo = (((size_t)ping * 2 + 1) * 2 + dir) * (64 * 2048);
        hbuf[basehi + (size_t)bb * 2048 + k] = (short)hb;
        hbuf[baselo + (size_t)bb * 2048 + k] = (short)lb;

        if (dir == 0) {
            if (t == lens[bb] - 1) out[(size_t)bb * (2 * H_) + k] = h;
        } else {
            if (t == T_ - 1) out[(size_t)bb * (2 * H_) + H_ + k] = h;
        }
    }
}

// ================= round-1 last-resort path =================
__global__ void init_state(float* __restrict__ hbuf, float* __restrict__ cbuf) {
    int n_h = 2 * 2 * H_ * B_;
    int n_c = 2 * H_ * B_;
    int stride = gridDim.x * blockDim.x;
    int i = blockIdx.x * blockDim.x + threadIdx.x;
    for (int idx = i; idx < n_h; idx += stride) hbuf[idx] = 0.f;
    for (int idx = i; idx < n_c; idx += stride) cbuf[idx] = 0.f;
}

__global__ void gather_x(const int* __restrict__ tokens, const float* __restrict__ embed,
                         float* __restrict__ x_t) {
    int idx = blockIdx.x * blockDim.x + threadIdx.x;
    int total = T_ * E_ * B_;
    if (idx >= total) return;
    int b = idx % B_;
    int r = idx / B_;
    int e = r % E_;
    int t = r / E_;
    int tok = tokens[t * B_ + b];
    x_t[idx] = embed[tok * E_ + e];
}

__global__ __launch_bounds__(256) void lstm_step(
    const float* __restrict__ x_t, const float* __restrict__ W_ih,
    const float* __restrict__ W_hh, const float* __restrict__ b_ih,
    const float* __restrict__ b_hh, const int* __restrict__ lens,
    const float* __restrict__ h_in, float* __restrict__ h_out,
    float* __restrict__ cbuf, float* __restrict__ out, int t)
{
    const int dir = blockIdx.x >> 8;
    const int kblk = blockIdx.x & 255;
    const int bpair = threadIdx.x & 31;
    const int kloc = threadIdx.x >> 5;
    const int k = kblk * 8 + kloc;
    const int b0 = bpair * 2;
    const int xt = dir ? (T_ - 1 - t) : t;
    const float* xrow = x_t + (size_t)xt * E_ * B_;
    const float* hrow = h_in + (size_t)dir * H_ * B_;
    float a0x = 0.f, a0y = 0.f, a1x = 0.f, a1y = 0.f;
    float a2x = 0.f, a2y = 0.f, a3x = 0.f, a3y = 0.f;
    {
        const float* w0 = W_ih + (size_t)(0 * H_ + k) * E_;
        const float* w1 = W_ih + (size_t)(1 * H_ + k) * E_;
        const float* w2 = W_ih + (size_t)(2 * H_ + k) * E_;
        const float* w3 = W_ih + (size_t)(3 * H_ + k) * E_;
#pragma unroll 4
        for (int kk = 0; kk < E_; ++kk) {
            float2 xv = *(const float2*)(xrow + kk * B_ + b0);
            float c0 = w0[kk], c1 = w1[kk], c2 = w2[kk], c3 = w3[kk];
            a0x += xv.x * c0; a0y += xv.y * c0;
            a1x += xv.x * c1; a1y += xv.y * c1;
            a2x += xv.x * c2; a2y += xv.y * c2;
            a3x += xv.x * c3; a3y += xv.y * c3;
        }
    }
    {
        const float* w0 = W_hh + (size_t)(0 * H_ + k) * H_;
        const float* w1 = W_hh + (size_t)(1 * H_ + k) * H_;
        const float* w2 = W_hh + (size_t)(2 * H_ + k) * H_;
        const float* w3 = W_hh + (size_t)(3 * H_ + k) * H_;
#pragma unroll 4
        for (int kk = 0; kk < H_; ++kk) {
            float2 hv = *(const float2*)(hrow + kk * B_ + b0);
            float c0 = w0[kk], c1 = w1[kk], c2 = w2[kk], c3 = w3[kk];
            a0x += hv.x * c0; a0y += hv.y * c0;
            a1x += hv.x * c1; a1y += hv.y * c1;
            a2x += hv.x * c2; a2y += hv.y * c2;
            a3x += hv.x * c3; a3y += hv.y * c3;
        }
    }
    const int j0 = 0 * H_ + k, j1 = 1 * H_ + k, j2 = 2 * H_ + k, j3 = 3 * H_ + k;
    const float bi = b_ih[j0] + b_hh[j0];
    const float bf = b_ih[j1] + b_hh[j1];
    const float bg = b_ih[j2] + b_hh[j2];
    const float bo = b_ih[j3] + b_hh[j3];
    float* cdir = cbuf + (size_t)dir * H_ * B_;
    float* hdir = h_out + (size_t)dir * H_ * B_;
#pragma unroll
    for (int s = 0; s < 2; ++s) {
        const int b = b0 + s;
        const float ai = (s == 0) ? a0x : a0y;
        const float af = (s == 0) ? a1x : a1y;
        const float ag = (s == 0) ? a2x : a2y;
        const float ao = (s == 0) ? a3x : a3y;
        const float iv = sigm(ai + bi);
        const float fv = sigm(af + bf);
        const float gv = tanhf(ag + bg);
        const float ov = sigm(ao + bo);
        const int sidx = k * B_ + b;
        const float c_old = cdir[sidx];
        const float c_new = fv * c_old + iv * gv;
        cdir[sidx] = c_new;
        const float h_new = ov * tanhf(c_new);
        hdir[sidx] = h_new;
        if (dir == 0) {
            if (t == lens[b] - 1) out[(size_t)b * (2 * H_) + k] = h_new;
        } else {
            if (t == T_ - 1) out[(size_t)b * (2 * H_) + H_ + k] = h_new;
        }
    }
}

// ================= launch =================
extern "C" void kernel_launch(void* const* d_in, const int* in_sizes, int n_in,
                              void* d_out, int out_size, void* d_ws, size_t ws_size,
                              hipStream_t stream) {
    const int*   tokens = (const int*)d_in[0];
    const int*   lens   = (const int*)d_in[1];
    const float* embed  = (const float*)d_in[2];
    const float* W_ih   = (const float*)d_in[3];
    const float* W_hh   = (const float*)d_in[4];
    const float* b_ih   = (const float*)d_in[5];
    const float* b_hh   = (const float*)d_in[6];
    float* out = (float*)d_out;

    // ---- new-path layout ----
    short* Ahi = (short*)d_ws;
    short* Alo = Ahi + APELEMS;
    short* BxP = Alo + APELEMS;
    short* BhP = BxP + BXELEMS;
    float* cb2n = (float*)(BhP + 2 * BHPING);
    float* phi  = cb2n + 262144;
    float* plo  = phi + 4194304;
    const size_t req_new = (size_t)((char*)(plo + 4194304) - (char*)d_ws);

    // ---- r2 layout ----
    const size_t SZ_W  = (size_t)8192 * R2K1;
    const size_t SZ_X  = (size_t)T_ * B_ * R2EPAD;
    const size_t SZ_HB = (size_t)2 * 2 * 2 * 64 * 2048;
    const size_t SZ_CB = (size_t)2 * 2048 * 64;
    const size_t SZ_PB = (size_t)64 * 4 * 256 * 64;
    short* Whi2  = (short*)d_ws;
    short* Wlo2  = Whi2 + SZ_W;
    short* xhiB = Wlo2 + SZ_W;
    short* xloB = xhiB + SZ_X;
    short* hb2  = xloB + SZ_X;
    short* zer  = hb2 + SZ_HB;
    float* cb2  = (float*)(zer + 128);
    float* pbuf = cb2 + SZ_CB;
    const size_t req_r2 = (size_t)((char*)(pbuf + SZ_PB) - (char*)d_ws);

    if (ws_size >= req_new) {
        init2<<<512, 256, 0, stream>>>(BhP, cb2n);
        pack_w<<<(int)((APELEMS + 255) / 256), 256, 0, stream>>>(W_ih, W_hh, Ahi, Alo);
        pack_x<<<(int)((BXELEMS + 255) / 256), 256, 0, stream>>>(tokens, embed, BxP);
        for (int t = 0; t < T_; ++t) {
            gemm_step<<<512, 512, 0, stream>>>(Ahi, Alo, BxP, BhP, phi, plo, t);
            update2<<<256, 256, 0, stream>>>(phi, plo, b_ih, b_hh, lens, cb2n, BhP, out, t);
        }
    } else if (ws_size >= req_r2) {
        init_ws2<<<1024, 256, 0, stream>>>(hb2, cb2, zer);
        {
            int total = 8192 * R2K1;
            conv_w<<<(total + 255) / 256, 256, 0, stream>>>(W_ih, W_hh, Whi2, Wlo2);
        }
        {
            int total = T_ * B_ * R2EPAD;
            conv_x<<<(total + 255) / 256, 256, 0, stream>>>(tokens, embed, xhiB, xloB);
        }
        for (int t = 0; t < T_; ++t) {
            gemm_partial<<<256, 512, 0, stream>>>(Whi2, Wlo2, xhiB, xloB, hb2, zer, pbuf, t);
            lstm_update<<<64, 256, 0, stream>>>(pbuf, b_ih, b_hh, lens, cb2, hb2, out, t);
        }
    } else {
        float* ws   = (float*)d_ws;
        float* x_t  = ws;
        float* hbuf = x_t + (size_t)T_ * E_ * B_;
        float* cbuf = hbuf + (size_t)2 * 2 * H_ * B_;
        init_state<<<256, 256, 0, stream>>>(hbuf, cbuf);
        {
            int total = T_ * E_ * B_;
            gather_x<<<(total + 255) / 256, 256, 0, stream>>>(tokens, embed, x_t);
        }
        for (int t = 0; t < T_; ++t) {
            const float* h_in  = hbuf + (size_t)(t & 1) * 2 * H_ * B_;
            float*       h_out = hbuf + (size_t)((t + 1) & 1) * 2 * H_ * B_;
            lstm_step<<<512, 256, 0, stream>>>(x_t, W_ih, W_hh, b_ih, b_hh, lens,
                                               h_in, h_out, cbuf, out, t);
        }
    }
}

// Round 5
// 4003.116 us; speedup vs baseline: 8.4981x; 1.1154x over previous
//
#include <hip/hip_runtime.h>
#include <math.h>

#define T_ 128
#define B_ 64
#define E_ 300
#define H_ 2048

// ======== new-path geometry ========
// K layout: [0,300) x | [300,320) zero-pad | [320,2368) h   -> K1 = 2368 = 74 ksteps of 32
#define K1   2368
#define XKS  10      // x ksteps (320/32)
#define NKS  74      // total ksteps
#define SPL  37      // ksteps per K-split (s=2)
#define APELEMS 19398656ull   // 8192 * 2368, per weight matrix (frag-major packed)
#define BXELEMS 5242880ull    // 128 t * 10 ks * 2 hl * 4 nf * 64 l * 8 j
#define BHPING  524288ull     // 64 ks * 16 nf * 64 l * 8 j   (shorts per ping)

typedef __attribute__((ext_vector_type(8))) short short8;
typedef __attribute__((ext_vector_type(4))) float float4v;

__device__ __forceinline__ unsigned f2bf(float f) {
    unsigned u = __float_as_uint(f);
    return (u + 0x7FFFu + ((u >> 16) & 1u)) >> 16;
}
__device__ __forceinline__ float bf2f(unsigned b) { return __uint_as_float(b << 16); }

__device__ __forceinline__ void gl_lds16(const void* g, void* l) {
    __builtin_amdgcn_global_load_lds(
        (const __attribute__((address_space(1))) unsigned int*)g,
        (__attribute__((address_space(3))) unsigned int*)l, 16, 0, 0);
}

__device__ __forceinline__ float sigm(float x) { return 1.f / (1.f + expf(-x)); }

// ================= new-path prologue =================

__global__ void init2(short* __restrict__ Bh, float* __restrict__ cb) {
    const int nB = 2 * (int)BHPING;     // shorts
    const int nC = 2 * 2048 * 64;       // floats
    int stride = gridDim.x * blockDim.x;
    int i = blockIdx.x * blockDim.x + threadIdx.x;
    for (int idx = i; idx < nB; idx += stride) Bh[idx] = 0;
    for (int idx = i; idx < nC; idx += stride) cb[idx] = 0.f;
}

// frag-major packed weights: [rb(64)][ks(74)][mf(8)][l(64)][j(8)]
// element = W[row = rb*128+mf*16+(l&15)][kr = ks*32+(l>>4)*8+j]
__global__ void pack_w(const float* __restrict__ Wih, const float* __restrict__ Whh,
                       short* __restrict__ Ahi, short* __restrict__ Alo) {
    long long idx = (long long)blockIdx.x * blockDim.x + threadIdx.x;
    if (idx >= (long long)APELEMS) return;
    int j  = (int)(idx & 7);
    int l  = (int)((idx >> 3) & 63);
    int mf = (int)((idx >> 9) & 7);
    int rest = (int)(idx >> 12);
    int ks = rest % 74;
    int rb = rest / 74;
    int row = rb * 128 + mf * 16 + (l & 15);
    int kr  = ks * 32 + (l >> 4) * 8 + j;
    float wv = 0.f;
    if (kr < 300)       wv = Wih[(size_t)row * 300 + kr];
    else if (kr >= 320) wv = Whh[(size_t)row * 2048 + (kr - 320)];
    unsigned hb = f2bf(wv);
    Ahi[idx] = (short)hb;
    Alo[idx] = (short)f2bf(wv - bf2f(hb));
}

// packed x: [t(128)][ks(10)][hl(2)][nf4(4)][l(64)][j(8)]
// col b = nf4*16+(l&15); kr = ks*32+(l>>4)*8+j
__global__ void pack_x(const int* __restrict__ tokens, const float* __restrict__ embed,
                       short* __restrict__ Bx) {
    long long idx = (long long)blockIdx.x * blockDim.x + threadIdx.x;
    if (idx >= (long long)BXELEMS) return;
    int j   = (int)(idx & 7);
    int l   = (int)((idx >> 3) & 63);
    int nf4 = (int)((idx >> 9) & 3);
    int hl  = (int)((idx >> 11) & 1);
    int rest = (int)(idx >> 12);
    int ks = rest % 10;
    int tt = rest / 10;
    int b  = nf4 * 16 + (l & 15);
    int kr = ks * 32 + (l >> 4) * 8 + j;
    float v = 0.f;
    if (kr < 300) {
        int tok = tokens[tt * 64 + b];
        v = embed[(size_t)tok * 300 + kr];
    }
    unsigned hb = f2bf(v);
    Bx[idx] = hl ? (short)f2bf(v - bf2f(hb)) : (short)hb;
}

// ================= new-path per-step GEMM =================
// TYPE 0 (Whi): 128 blocks = rb(64) x s(2); M=128, N=256 (cg: d0hi,d0lo,d1hi,d1lo)
//               wavegrid 2(M)x4(N); epilogue sums hi+lo col pairs -> phi[s][8192][128]
// TYPE 1 (Wlo): 128 blocks; M=128, N=128 (cg: d0hi,d1hi); wavegrid 4x2 -> plo[s][8192][128]
//
// K-loop: 4-buffer counted-vmcnt pipeline, prefetch distance 3. Per stage, each
// thread issues a FIXED load count (TYPE0: 3, TYPE1: 2), so s_waitcnt vmcnt(6)/(4)
// at the per-iteration barrier waits exactly for tile it+1 while tiles it+2, it+3
// stay in flight across the barrier. Tail uses uniform clamped over-fetch (the
// duplicate stage targets buf (it+3)&3, whose prior tile was consumed at it-1).
template<int TYPE>
__device__ __forceinline__ void gemm_body(
    int bb, short* lds,
    const short* __restrict__ Ahi, const short* __restrict__ Alo,
    const short* __restrict__ Bx, const short* __restrict__ Bh,
    float* __restrict__ phi, float* __restrict__ plo, int t)
{
    const int rb = bb >> 1, s = bb & 1;
    const int tid = (int)threadIdx.x;
    const int w = tid >> 6, l = tid & 63;
    const int ping = t & 1;
    constexpr int MF = TYPE ? 2 : 4;
    const short* Ap = TYPE ? Alo : Ahi;

    const int ks0 = SPL * s;
    const int nks = SPL;

    float4v acc[MF][4];
#pragma unroll
    for (int i = 0; i < MF; ++i)
#pragma unroll
        for (int n = 0; n < 4; ++n) acc[i][n] = (float4v){0.f, 0.f, 0.f, 0.f};

    auto stage = [&](int ks, int buf) {
        short* As = lds + buf * 12288;
        short* Bs = As + 4096;
        // A: 512 chunks of 16B, linear
        {
            const short* src = Ap + ((size_t)(rb * 74 + ks) * 512 + tid) * 8;
            gl_lds16(src, As + tid * 8);
        }
        // B
        const int NB = TYPE ? 1 : 2;
#pragma unroll
        for (int q = 0; q < NB; ++q) {
            int c = q * 512 + tid;
            int nt = c >> 6, ll = c & 63;
            int dsel, hl, nf;
            if (TYPE) { dsel = nt >> 2; hl = 0; nf = dsel * 8 + (nt & 3); }
            else      { nf = nt; dsel = nf >> 3; hl = (nf >> 2) & 1; }
            const short* src;
            if (ks < XKS) {
                int xt = dsel ? (127 - t) : t;
                src = Bx + (((size_t)(xt * 10 + ks) * 2 + hl) * 4 + (nf & 3)) * 512 + ll * 8;
            } else {
                src = Bh + (size_t)ping * BHPING + ((size_t)(ks - XKS) * 16 + nf) * 512 + ll * 8;
            }
            gl_lds16(src, Bs + c * 8);
        }
    };

    const int wm = TYPE ? (w >> 1) : (w >> 2);
    const int wn = TYPE ? (w & 1) : (w & 3);

    // prologue: tiles 0,1,2 staged; wait tile0 landed (tiles 1,2 in flight)
    stage(ks0, 0);
    stage(ks0 + 1, 1);
    stage(ks0 + 2, 2);
    if constexpr (TYPE) { asm volatile("s_waitcnt vmcnt(4)" ::: "memory"); }
    else                { asm volatile("s_waitcnt vmcnt(6)" ::: "memory"); }
    __builtin_amdgcn_s_barrier();
    __builtin_amdgcn_sched_barrier(0);

    for (int it = 0; it < nks; ++it) {
        const int buf = it & 3;
        int pre = it + 3; if (pre > nks - 1) pre = nks - 1;   // clamped over-fetch
        stage(ks0 + pre, (it + 3) & 3);

        short* As = lds + buf * 12288;
        short* Bs = As + 4096;
        short8 a[MF], b[4];
#pragma unroll
        for (int i = 0; i < MF; ++i)
            a[i] = *(const short8*)(As + ((wm * MF + i) * 64 + l) * 8);
#pragma unroll
        for (int n = 0; n < 4; ++n)
            b[n] = *(const short8*)(Bs + ((wn * 4 + n) * 64 + l) * 8);
        __builtin_amdgcn_s_setprio(1);
#pragma unroll
        for (int i = 0; i < MF; ++i)
#pragma unroll
            for (int n = 0; n < 4; ++n)
                acc[i][n] = __builtin_amdgcn_mfma_f32_16x16x32_bf16(a[i], b[n], acc[i][n], 0, 0, 0);
        __builtin_amdgcn_s_setprio(0);

        // wait tile it+1 landed; tiles it+2, it+3 stay in flight across barrier
        if constexpr (TYPE) { asm volatile("s_waitcnt vmcnt(4)" ::: "memory"); }
        else                { asm volatile("s_waitcnt vmcnt(6)" ::: "memory"); }
        __builtin_amdgcn_s_barrier();
        __builtin_amdgcn_sched_barrier(0);
    }

    // drain stray clamped prefetches before LDS reuse / endpgm
    asm volatile("s_waitcnt vmcnt(0)" ::: "memory");
    __builtin_amdgcn_s_barrier();
    __builtin_amdgcn_sched_barrier(0);

    if (TYPE == 0) {
        // reduce col pairs (wn 0<-1 for d0, 2<-3 for d1) via LDS, then write phi
        float* red = (float*)lds;   // 32KB scratch
#pragma unroll
        for (int rnd = 0; rnd < 2; ++rnd) {
            __syncthreads();
            if (wn == rnd * 2 + 1) {
#pragma unroll
                for (int i = 0; i < 4; ++i)
#pragma unroll
                    for (int n = 0; n < 4; ++n)
                        *(float4v*)(red + ((wm * 16 + i * 4 + n) * 64 + l) * 4) = acc[i][n];
            }
            __syncthreads();
            if (wn == rnd * 2) {
#pragma unroll
                for (int i = 0; i < 4; ++i)
#pragma unroll
                    for (int n = 0; n < 4; ++n) {
                        float4v v = *(const float4v*)(red + ((wm * 16 + i * 4 + n) * 64 + l) * 4);
                        acc[i][n] += v;
                    }
            }
        }
        if (!(wn & 1)) {
            const int d = wn >> 1;
#pragma unroll
            for (int i = 0; i < 4; ++i)
#pragma unroll
                for (int n = 0; n < 4; ++n)
#pragma unroll
                    for (int r = 0; r < 4; ++r) {
                        int row = rb * 128 + wm * 64 + i * 16 + (l >> 4) * 4 + r;
                        int col = d * 64 + n * 16 + (l & 15);
                        phi[((size_t)s * 8192 + row) * 128 + col] = acc[i][n][r];
                    }
        }
    } else {
#pragma unroll
        for (int i = 0; i < 2; ++i)
#pragma unroll
            for (int n = 0; n < 4; ++n)
#pragma unroll
                for (int r = 0; r < 4; ++r) {
                    int nt = wn * 4 + n;
                    int row = rb * 128 + (wm * 2 + i) * 16 + (l >> 4) * 4 + r;
                    int col = (nt >> 2) * 64 + (nt & 3) * 16 + (l & 15);
                    plo[((size_t)s * 8192 + row) * 128 + col] = acc[i][n][r];
                }
    }
}

__global__ __launch_bounds__(512, 2) void gemm_step(
    const short* __restrict__ Ahi, const short* __restrict__ Alo,
    const short* __restrict__ Bx, const short* __restrict__ Bh,
    float* __restrict__ phi, float* __restrict__ plo, int t)
{
    __shared__ short lds[49152];   // 4 bufs x 24KB = 96 KB
    if (blockIdx.x < 128) gemm_body<0>(blockIdx.x, lds, Ahi, Alo, Bx, Bh, phi, plo, t);
    else                  gemm_body<1>(blockIdx.x - 128, lds, Ahi, Alo, Bx, Bh, phi, plo, t);
}

// ================= new-path per-step update =================
__global__ __launch_bounds__(256) void update2(
    const float* __restrict__ phi, const float* __restrict__ plo,
    const float* __restrict__ b_ih, const float* __restrict__ b_hh,
    const int* __restrict__ lens,
    float* __restrict__ cbuf,       // [dir][2048][64] f32
    short* __restrict__ Bh,         // packed h hi/lo
    float* __restrict__ out, int t)
{
    int tid0 = blockIdx.x * 256 + threadIdx.x;
    for (int item = tid0; item < 262144; item += 65536) {
        int b = item & 63, k = (item >> 6) & 2047, dir = item >> 17;
        float g[4];
#pragma unroll
        for (int gg = 0; gg < 4; ++gg) {
            int row = gg * 2048 + k;
            float v = 0.f;
#pragma unroll
            for (int s = 0; s < 2; ++s) v += phi[((size_t)s * 8192 + row) * 128 + dir * 64 + b];
#pragma unroll
            for (int s = 0; s < 2; ++s) v += plo[((size_t)s * 8192 + row) * 128 + dir * 64 + b];
            g[gg] = v + b_ih[row] + b_hh[row];
        }
        float iv = sigm(g[0]);
        float fv = sigm(g[1]);
        float gv = tanhf(g[2]);
        float ov = sigm(g[3]);
        size_t cidx = ((size_t)dir * 2048 + k) * 64 + b;
        float c = fv * cbuf[cidx] + iv * gv;
        cbuf[cidx] = c;
        float h = ov * tanhf(c);

        int kk = k & 31, ksh = k >> 5;
        int jj = kk & 7, ll = (kk >> 3) * 16 + (b & 15), sub = b >> 4;
        int pingW = (t + 1) & 1;
        size_t baseh = (size_t)pingW * BHPING + ((size_t)ksh * 16 + (dir * 2) * 4 + sub) * 512 + ll * 8 + jj;
        size_t basel = (size_t)pingW * BHPING + ((size_t)ksh * 16 + (dir * 2 + 1) * 4 + sub) * 512 + ll * 8 + jj;
        unsigned hb = f2bf(h);
        Bh[baseh] = (short)hb;
        Bh[basel] = (short)f2bf(h - bf2f(hb));

        if (dir == 0) { if (t == lens[b] - 1) out[(size_t)b * 4096 + k] = h; }
        else          { if (t == 127)         out[(size_t)b * 4096 + 2048 + k] = h; }
    }
}

// ======================================================================
// ================= round-2 fallback path (proven, ~102 MiB) ===========
// ======================================================================
#define R2K1    2368
#define R2EPAD  304
#define R2HOFF  304
#define R2HEND  2352
#define R2SEGSTEPS 74
#define R2REALSTEPS 222
#define R2SPLITSTEPS 56

__global__ void init_ws2(short* __restrict__ hb, float* __restrict__ cb,
                         short* __restrict__ zer) {
    const int nH = 2 * 2 * 2 * 64 * 2048;
    const int nC = 2 * 2048 * 64;
    int stride = gridDim.x * blockDim.x;
    int i = blockIdx.x * blockDim.x + threadIdx.x;
    for (int idx = i; idx < nH; idx += stride) hb[idx] = 0;
    for (int idx = i; idx < nC; idx += stride) cb[idx] = 0.f;
    for (int idx = i; idx < 128; idx += stride) zer[idx] = 0;
}

__global__ void conv_w(const float* __restrict__ Wih, const float* __restrict__ Whh,
                       short* __restrict__ whi, short* __restrict__ wlo) {
    int idx = blockIdx.x * blockDim.x + threadIdx.x;
    const int total = 8192 * R2K1;
    if (idx >= total) return;
    int j = idx / R2K1;
    int col = idx - j * R2K1;
    float w = 0.f;
    if (col < E_) w = Wih[(size_t)j * E_ + col];
    else if (col >= R2HOFF && col < R2HEND) w = Whh[(size_t)j * H_ + (col - R2HOFF)];
    unsigned hb = f2bf(w);
    whi[idx] = (short)hb;
    wlo[idx] = (short)f2bf(w - bf2f(hb));
}

__global__ void conv_x(const int* __restrict__ tokens, const float* __restrict__ embed,
                       short* __restrict__ xhi, short* __restrict__ xlo) {
    int idx = blockIdx.x * blockDim.x + threadIdx.x;
    const int total = T_ * B_ * R2EPAD;
    if (idx >= total) return;
    int t = idx / (B_ * R2EPAD);
    int r = idx - t * (B_ * R2EPAD);
    int bb = r / R2EPAD;
    int e = r - bb * R2EPAD;
    float v = 0.f;
    if (e < E_) {
        int tok = tokens[t * B_ + bb];
        v = embed[(size_t)tok * E_ + e];
    }
    unsigned hb = f2bf(v);
    xhi[idx] = (short)hb;
    xlo[idx] = (short)f2bf(v - bf2f(hb));
}

__global__ __launch_bounds__(512) void gemm_partial(
    const short* __restrict__ Whi, const short* __restrict__ Wlo,
    const short* __restrict__ xhi, const short* __restrict__ xlo,
    const short* __restrict__ hbuf,
    const short* __restrict__ zeros,
    float* __restrict__ pbuf, int t)
{
    __shared__ short As[2][8192];
    __shared__ short Bs[2][2048];

    const int bx  = blockIdx.x;
    const int s   = bx & 3;
    const int kt  = (bx >> 2) & 31;
    const int dir = bx >> 7;
    const int tid = threadIdx.x;
    const int w   = tid >> 6;
    const int l   = tid & 63;
    const int ping = t & 1;
    const int xt   = dir ? (T_ - 1 - t) : t;

    int jA[2], cA[2];
#pragma unroll
    for (int q = 0; q < 2; ++q) {
        int idx = (w * 2 + q) * 64 + l;
        cA[q] = idx >> 8;
        int row = idx & 255;
        jA[q] = (row >> 6) * 2048 + kt * 64 + (row & 63);
    }
    int cB = 0, bB = 0;
    if (w < 4) { int idx = w * 64 + l; cB = idx >> 6; bB = idx & 63; }

    const int lhi = l >> 4, llo = l & 15;
    const int rowbase = (w >> 1) * 64 + (w & 1) * 32;

    float4v acc[2][4];
#pragma unroll
    for (int a = 0; a < 2; ++a)
#pragma unroll
        for (int b = 0; b < 4; ++b) acc[a][b] = (float4v){0.f, 0.f, 0.f, 0.f};

    auto stage = [&](int g, int buf) {
        const bool dummy = (g >= R2REALSTEPS);
        const int seg = dummy ? 2 : g / R2SEGSTEPS;
        const int ss  = dummy ? 0 : g - seg * R2SEGSTEPS;
        const int kbase = ss * 32;
        const short* Wsel = (seg < 2) ? Whi : Wlo;
        const int hl = (seg == 1) ? 1 : 0;
        const short* xsel = (seg == 1) ? xlo : xhi;
        const short* hsel = hbuf + (((size_t)ping * 2 + hl) * 2 + dir) * (64 * 2048);
#pragma unroll
        for (int q = 0; q < 2; ++q) {
            const short* src = Wsel + (size_t)jA[q] * R2K1 + kbase + 8 * cA[q];
            gl_lds16(src, &As[buf][(w * 2 + q) * 64 * 8]);
        }
        if (w < 4) {
            int row8 = kbase + 8 * cB;
            const short* src;
            if (dummy || row8 >= R2HEND) src = zeros;
            else if (row8 < R2EPAD)      src = xsel + ((size_t)xt * 64 + bB) * R2EPAD + row8;
            else                         src = hsel + (size_t)bB * 2048 + (row8 - R2HOFF);
            gl_lds16(src, &Bs[buf][w * 64 * 8]);
        }
    };

    const int g0 = s * R2SPLITSTEPS;
    stage(g0, 0);

    for (int it = 0; it < R2SPLITSTEPS; ++it) {
        const int buf = it & 1;
        if (it + 1 < R2SPLITSTEPS) stage(g0 + it + 1, buf ^ 1);
        __syncthreads();
        short8 a0 = *(const short8*)&As[buf][(lhi * 256 + rowbase + llo) * 8];
        short8 a1 = *(const short8*)&As[buf][(lhi * 256 + rowbase + 16 + llo) * 8];
        short8 b0 = *(const short8*)&Bs[buf][(lhi * 64 + llo) * 8];
        short8 b1 = *(const short8*)&Bs[buf][(lhi * 64 + 16 + llo) * 8];
        short8 b2 = *(const short8*)&Bs[buf][(lhi * 64 + 32 + llo) * 8];
        short8 b3 = *(const short8*)&Bs[buf][(lhi * 64 + 48 + llo) * 8];
        acc[0][0] = __builtin_amdgcn_mfma_f32_16x16x32_bf16(a0, b0, acc[0][0], 0, 0, 0);
        acc[0][1] = __builtin_amdgcn_mfma_f32_16x16x32_bf16(a0, b1, acc[0][1], 0, 0, 0);
        acc[0][2] = __builtin_amdgcn_mfma_f32_16x16x32_bf16(a0, b2, acc[0][2], 0, 0, 0);
        acc[0][3] = __builtin_amdgcn_mfma_f32_16x16x32_bf16(a0, b3, acc[0][3], 0, 0, 0);
        acc[1][0] = __builtin_amdgcn_mfma_f32_16x16x32_bf16(a1, b0, acc[1][0], 0, 0, 0);
        acc[1][1] = __builtin_amdgcn_mfma_f32_16x16x32_bf16(a1, b1, acc[1][1], 0, 0, 0);
        acc[1][2] = __builtin_amdgcn_mfma_f32_16x16x32_bf16(a1, b2, acc[1][2], 0, 0, 0);
        acc[1][3] = __builtin_amdgcn_mfma_f32_16x16x32_bf16(a1, b3, acc[1][3], 0, 0, 0);
        __syncthreads();
    }

    float* pb = pbuf + (((size_t)(dir * 32 + kt) * 4 + s) * 256) * 64;
#pragma unroll
    for (int qm = 0; qm < 2; ++qm)
#pragma unroll
        for (int nb = 0; nb < 4; ++nb)
#pragma unroll
            for (int r = 0; r < 4; ++r) {
                int row = rowbase + qm * 16 + lhi * 4 + r;
                int col = nb * 16 + llo;
                pb[row * 64 + col] = acc[qm][nb][r];
            }
}

__global__ __launch_bounds__(256) void lstm_update(
    const float* __restrict__ pbuf,
    const float* __restrict__ b_ih, const float* __restrict__ b_hh,
    const int* __restrict__ lens,
    float* __restrict__ cbuf,
    short* __restrict__ hbuf,
    float* __restrict__ out, int t)
{
    const int bx = blockIdx.x;
    const int kt = bx & 31, dir = bx >> 5;
    const float* pb = pbuf + (size_t)(dir * 32 + kt) * 4 * 256 * 64;
    const int ping = (t + 1) & 1;

    for (int idx = threadIdx.x; idx < 4096; idx += 256) {
        const int q = idx >> 6, bb = idx & 63;
        const int k = kt * 64 + q;
        float gv[4];
#pragma unroll
        for (int gg = 0; gg < 4; ++gg) {
            const int r = gg * 64 + q;
            float v = 0.f;
#pragma unroll
            for (int s2 = 0; s2 < 4; ++s2) v += pb[(s2 * 256 + r) * 64 + bb];
            const int j = gg * 2048 + k;
            gv[gg] = v + b_ih[j] + b_hh[j];
        }
        const float iv = sigm(gv[0]);
        const float fv = sigm(gv[1]);
        const float g2 = tanhf(gv[2]);
        const float ov = sigm(gv[3]);
        const size_t cidx = ((size_t)dir * 2048 + k) * 64 + bb;
        const float c = fv * cbuf[cidx] + iv * g2;
        cbuf[cidx] = c;
        const float h = ov * tanhf(c);

        const unsigned hb = f2bf(h);
        const float hhi = bf2f(hb);
        const unsigned lb = f2bf(h - hhi);
        const size_t basehi = (((size_t)ping * 2 + 0) * 2 + dir) * (64 * 2048);
        const size_t baselo = (((size_t)ping * 2 + 1) * 2 + dir) * (64 * 2048);
        hbuf[basehi + (size_t)bb * 2048 + k] = (short)hb;
        hbuf[baselo + (size_t)bb * 2048 + k] = (short)lb;

        if (dir == 0) {
            if (t == lens[bb] - 1) out[(size_t)bb * (2 * H_) + k] = h;
        } else {
            if (t == T_ - 1) out[(size_t)bb * (2 * H_) + H_ + k] = h;
        }
    }
}

// ================= round-1 last-resort path =================
__global__ void init_state(float* __restrict__ hbuf, float* __restrict__ cbuf) {
    int n_h = 2 * 2 * H_ * B_;
    int n_c = 2 * H_ * B_;
    int stride = gridDim.x * blockDim.x;
    int i = blockIdx.x * blockDim.x + threadIdx.x;
    for (int idx = i; idx < n_h; idx += stride) hbuf[idx] = 0.f;
    for (int idx = i; idx < n_c; idx += stride) cbuf[idx] = 0.f;
}

__global__ void gather_x(const int* __restrict__ tokens, const float* __restrict__ embed,
                         float* __restrict__ x_t) {
    int idx = blockIdx.x * blockDim.x + threadIdx.x;
    int total = T_ * E_ * B_;
    if (idx >= total) return;
    int b = idx % B_;
    int r = idx / B_;
    int e = r % E_;
    int t = r / E_;
    int tok = tokens[t * B_ + b];
    x_t[idx] = embed[tok * E_ + e];
}

__global__ __launch_bounds__(256) void lstm_step(
    const float* __restrict__ x_t, const float* __restrict__ W_ih,
    const float* __restrict__ W_hh, const float* __restrict__ b_ih,
    const float* __restrict__ b_hh, const int* __restrict__ lens,
    const float* __restrict__ h_in, float* __restrict__ h_out,
    float* __restrict__ cbuf, float* __restrict__ out, int t)
{
    const int dir = blockIdx.x >> 8;
    const int kblk = blockIdx.x & 255;
    const int bpair = threadIdx.x & 31;
    const int kloc = threadIdx.x >> 5;
    const int k = kblk * 8 + kloc;
    const int b0 = bpair * 2;
    const int xt = dir ? (T_ - 1 - t) : t;
    const float* xrow = x_t + (size_t)xt * E_ * B_;
    const float* hrow = h_in + (size_t)dir * H_ * B_;
    float a0x = 0.f, a0y = 0.f, a1x = 0.f, a1y = 0.f;
    float a2x = 0.f, a2y = 0.f, a3x = 0.f, a3y = 0.f;
    {
        const float* w0 = W_ih + (size_t)(0 * H_ + k) * E_;
        const float* w1 = W_ih + (size_t)(1 * H_ + k) * E_;
        const float* w2 = W_ih + (size_t)(2 * H_ + k) * E_;
        const float* w3 = W_ih + (size_t)(3 * H_ + k) * E_;
#pragma unroll 4
        for (int kk = 0; kk < E_; ++kk) {
            float2 xv = *(const float2*)(xrow + kk * B_ + b0);
            float c0 = w0[kk], c1 = w1[kk], c2 = w2[kk], c3 = w3[kk];
            a0x += xv.x * c0; a0y += xv.y * c0;
            a1x += xv.x * c1; a1y += xv.y * c1;
            a2x += xv.x * c2; a2y += xv.y * c2;
            a3x += xv.x * c3; a3y += xv.y * c3;
        }
    }
    {
        const float* w0 = W_hh + (size_t)(0 * H_ + k) * H_;
        const float* w1 = W_hh + (size_t)(1 * H_ + k) * H_;
        const float* w2 = W_hh + (size_t)(2 * H_ + k) * H_;
        const float* w3 = W_hh + (size_t)(3 * H_ + k) * H_;
#pragma unroll 4
        for (int kk = 0; kk < H_; ++kk) {
            float2 hv = *(const float2*)(hrow + kk * B_ + b0);
            float c0 = w0[kk], c1 = w1[kk], c2 = w2[kk], c3 = w3[kk];
            a0x += hv.x * c0; a0y += hv.y * c0;
            a1x += hv.x * c1; a1y += hv.y * c1;
            a2x += hv.x * c2; a2y += hv.y * c2;
            a3x += hv.x * c3; a3y += hv.y * c3;
        }
    }
    const int j0 = 0 * H_ + k, j1 = 1 * H_ + k, j2 = 2 * H_ + k, j3 = 3 * H_ + k;
    const float bi = b_ih[j0] + b_hh[j0];
    const float bf = b_ih[j1] + b_hh[j1];
    const float bg = b_ih[j2] + b_hh[j2];
    const float bo = b_ih[j3] + b_hh[j3];
    float* cdir = cbuf + (size_t)dir * H_ * B_;
    float* hdir = h_out + (size_t)dir * H_ * B_;
#pragma unroll
    for (int s = 0; s < 2; ++s) {
        const int b = b0 + s;
        const float ai = (s == 0) ? a0x : a0y;
        const float af = (s == 0) ? a1x : a1y;
        const float ag = (s == 0) ? a2x : a2y;
        const float ao = (s == 0) ? a3x : a3y;
        const float iv = sigm(ai + bi);
        const float fv = sigm(af + bf);
        const float gv = tanhf(ag + bg);
        const float ov = sigm(ao + bo);
        const int sidx = k * B_ + b;
        const float c_old = cdir[sidx];
        const float c_new = fv * c_old + iv * gv;
        cdir[sidx] = c_new;
        const float h_new = ov * tanhf(c_new);
        hdir[sidx] = h_new;
        if (dir == 0) {
            if (t == lens[b] - 1) out[(size_t)b * (2 * H_) + k] = h_new;
        } else {
            if (t == T_ - 1) out[(size_t)b * (2 * H_) + H_ + k] = h_new;
        }
    }
}

// ================= launch =================
extern "C" void kernel_launch(void* const* d_in, const int* in_sizes, int n_in,
                              void* d_out, int out_size, void* d_ws, size_t ws_size,
                              hipStream_t stream) {
    const int*   tokens = (const int*)d_in[0];
    const int*   lens   = (const int*)d_in[1];
    const float* embed  = (const float*)d_in[2];
    const float* W_ih   = (const float*)d_in[3];
    const float* W_hh   = (const float*)d_in[4];
    const float* b_ih   = (const float*)d_in[5];
    const float* b_hh   = (const float*)d_in[6];
    float* out = (float*)d_out;

    // ---- new-path layout ----
    short* Ahi = (short*)d_ws;
    short* Alo = Ahi + APELEMS;
    short* BxP = Alo + APELEMS;
    short* BhP = BxP + BXELEMS;
    float* cb2n = (float*)(BhP + 2 * BHPING);
    float* phi  = cb2n + 262144;
    float* plo  = phi + 2097152;    // [2][8192][128]
    const size_t req_new = (size_t)((char*)(plo + 2097152) - (char*)d_ws);

    // ---- r2 layout ----
    const size_t SZ_W  = (size_t)8192 * R2K1;
    const size_t SZ_X  = (size_t)T_ * B_ * R2EPAD;
    const size_t SZ_HB = (size_t)2 * 2 * 2 * 64 * 2048;
    const size_t SZ_CB = (size_t)2 * 2048 * 64;
    const size_t SZ_PB = (size_t)64 * 4 * 256 * 64;
    short* Whi2  = (short*)d_ws;
    short* Wlo2  = Whi2 + SZ_W;
    short* xhiB = Wlo2 + SZ_W;
    short* xloB = xhiB + SZ_X;
    short* hb2  = xloB + SZ_X;
    short* zer  = hb2 + SZ_HB;
    float* cb2  = (float*)(zer + 128);
    float* pbuf = cb2 + SZ_CB;
    const size_t req_r2 = (size_t)((char*)(pbuf + SZ_PB) - (char*)d_ws);

    if (ws_size >= req_new) {
        init2<<<512, 256, 0, stream>>>(BhP, cb2n);
        pack_w<<<(int)((APELEMS + 255) / 256), 256, 0, stream>>>(W_ih, W_hh, Ahi, Alo);
        pack_x<<<(int)((BXELEMS + 255) / 256), 256, 0, stream>>>(tokens, embed, BxP);
        for (int t = 0; t < T_; ++t) {
            gemm_step<<<256, 512, 0, stream>>>(Ahi, Alo, BxP, BhP, phi, plo, t);
            update2<<<256, 256, 0, stream>>>(phi, plo, b_ih, b_hh, lens, cb2n, BhP, out, t);
        }
    } else if (ws_size >= req_r2) {
        init_ws2<<<1024, 256, 0, stream>>>(hb2, cb2, zer);
        {
            int total = 8192 * R2K1;
            conv_w<<<(total + 255) / 256, 256, 0, stream>>>(W_ih, W_hh, Whi2, Wlo2);
        }
        {
            int total = T_ * B_ * R2EPAD;
            conv_x<<<(total + 255) / 256, 256, 0, stream>>>(tokens, embed, xhiB, xloB);
        }
        for (int t = 0; t < T_; ++t) {
            gemm_partial<<<256, 512, 0, stream>>>(Whi2, Wlo2, xhiB, xloB, hb2, zer, pbuf, t);
            lstm_update<<<64, 256, 0, stream>>>(pbuf, b_ih, b_hh, lens, cb2, hb2, out, t);
        }
    } else {
        float* ws   = (float*)d_ws;
        float* x_t  = ws;
        float* hbuf = x_t + (size_t)T_ * E_ * B_;
        float* cbuf = hbuf + (size_t)2 * 2 * H_ * B_;
        init_state<<<256, 256, 0, stream>>>(hbuf, cbuf);
        {
            int total = T_ * E_ * B_;
            gather_x<<<(total + 255) / 256, 256, 0, stream>>>(tokens, embed, x_t);
        }
        for (int t = 0; t < T_; ++t) {
            const float* h_in  = hbuf + (size_t)(t & 1) * 2 * H_ * B_;
            float*       h_out = hbuf + (size_t)((t + 1) & 1) * 2 * H_ * B_;
            lstm_step<<<512, 256, 0, stream>>>(x_t, W_ih, W_hh, b_ih, b_hh, lens,
                                               h_in, h_out, cbuf, out, t);
        }
    }
}